// Round 17
// baseline (3075.502 us; speedup 1.0000x reference)
//
#include <hip/hip_runtime.h>
#include <cstdint>

typedef short  short8  __attribute__((ext_vector_type(8)));
typedef unsigned short ushort8 __attribute__((ext_vector_type(8)));
typedef _Float16 half8 __attribute__((ext_vector_type(8)));
typedef float  f32x4   __attribute__((ext_vector_type(4)));
typedef unsigned long long u64;

#define NPOS 2500
#define NA   22500
#define TOPN 6000
#define NKEEP 300
#define NBUCK 65536
#define THRESH 512
#define NSUB 8192
#define KSTEPS 392   // 25088 / 64
#define RANKBLKS 22  // ceil(22500/1024)

// ---- diagnostic repeat factors (idempotent; pins the remaining unmeasured kernels) ----
#define REP_K1  8
#define REP_K5  12
#define REP_K7  16
#define REP_K8  8
#define REP_K9A 8
#define REP_K9B 16
#define REP_K4S 8

__device__ __forceinline__ unsigned short f2bf(float f) {
  unsigned u = __float_as_uint(f);
  return (unsigned short)((u + 0x7FFFu + ((u >> 16) & 1u)) >> 16);
}

// ============ K1 (REP): patchify conv f32 GEMM + fused w_rpn transpose/split + hist zero ============
__global__ __launch_bounds__(256) void k1_gemm(const float* __restrict__ Asrc,
    const float* __restrict__ Bsrc, float* __restrict__ P, int klen,
    const float* __restrict__ wr, unsigned short* __restrict__ Whi,
    unsigned short* __restrict__ Wlo, int* __restrict__ histbuf)
{
  {
    int gtid = ((blockIdx.z * gridDim.y + blockIdx.y) * gridDim.x + blockIdx.x) * 256
             + threadIdx.x;
    int nth = gridDim.x * gridDim.y * gridDim.z * 256;
    if (gtid < NBUCK + 1 + 256) histbuf[gtid] = 0;
    for (int e = gtid; e < 512 * 4608; e += nth) {
      int n = e / 4608, r = e - n * 4608;
      int s = r >> 9, c = r & 511;
      float w = wr[n * 4608 + c * 9 + s] * 1024.f;
      _Float16 hi = (_Float16)w;
      _Float16 lo = (_Float16)(w - (float)hi);
      ((_Float16*)Whi)[e] = hi;
      ((_Float16*)Wlo)[e] = lo;
    }
  }

  __shared__ float As[32][128];
  __shared__ float Bs[32][132];
  int tid = threadIdx.x;
  int tx = tid & 15, ty = tid >> 4;
  int mt = blockIdx.x, nt = blockIdx.y;
  int m0 = mt * 128, n0 = nt * 128;
  int kbase = blockIdx.z * klen;

  int m_loc = tid & 127;
  int half = tid >> 7;
  int gm = m0 + m_loc;
  int y = gm / 50, x = gm - y * 50;
  bool mok = gm < NPOS;

  float acc[8][8];
  for (int rep = 0; rep < REP_K1; ++rep) {
#pragma unroll
  for (int i = 0; i < 8; ++i)
#pragma unroll
    for (int j = 0; j < 8; ++j) acc[i][j] = 0.f;

  for (int kt = 0; kt < klen; kt += 32) {
    int kb = kbase + kt;
    int k0 = kb + half * 16;
    int ci = k0 >> 8, r = (k0 >> 4) & 15;
    const float* src = Asrc + ci * 640000 + (y * 16 + r) * 800 + x * 16;
#pragma unroll
    for (int j = 0; j < 4; ++j) {
      float4 v = mok ? *(const float4*)(src + j * 4) : make_float4(0.f, 0.f, 0.f, 0.f);
      As[half * 16 + j * 4 + 0][m_loc] = v.x;
      As[half * 16 + j * 4 + 1][m_loc] = v.y;
      As[half * 16 + j * 4 + 2][m_loc] = v.z;
      As[half * 16 + j * 4 + 3][m_loc] = v.w;
    }
#pragma unroll
    for (int i = 0; i < 4; ++i) {
      int e = i * 256 + tid;
      int k4 = e & 7, n = e >> 3;
      float4 v = *(const float4*)(Bsrc + (size_t)(n0 + n) * 768 + kb + k4 * 4);
      Bs[k4 * 4 + 0][n] = v.x;
      Bs[k4 * 4 + 1][n] = v.y;
      Bs[k4 * 4 + 2][n] = v.z;
      Bs[k4 * 4 + 3][n] = v.w;
    }
    __syncthreads();
#pragma unroll 8
    for (int k = 0; k < 32; ++k) {
      float4 a0 = *(const float4*)&As[k][ty * 8];
      float4 a1 = *(const float4*)&As[k][ty * 8 + 4];
      float4 b0 = *(const float4*)&Bs[k][tx * 8];
      float4 b1 = *(const float4*)&Bs[k][tx * 8 + 4];
      float av[8] = {a0.x, a0.y, a0.z, a0.w, a1.x, a1.y, a1.z, a1.w};
      float bv[8] = {b0.x, b0.y, b0.z, b0.w, b1.x, b1.y, b1.z, b1.w};
#pragma unroll
      for (int i2 = 0; i2 < 8; ++i2)
#pragma unroll
        for (int j2 = 0; j2 < 8; ++j2) acc[i2][j2] += av[i2] * bv[j2];
    }
    __syncthreads();
  }
  }  // rep
  float* Pp = P + ((size_t)(blockIdx.z * 20 + mt) * 4 + nt) * 16384;
#pragma unroll
  for (int i = 0; i < 8; ++i) {
    float4 v0 = {acc[i][0], acc[i][1], acc[i][2], acc[i][3]};
    float4 v1 = {acc[i][4], acc[i][5], acc[i][6], acc[i][7]};
    *(float4*)&Pp[(ty * 8 + i) * 128 + tx * 8] = v0;
    *(float4*)&Pp[(ty * 8 + i) * 128 + tx * 8 + 4] = v1;
  }
}

// kred1: reduce k1 partials -> feat_t f32 + feat hi/lo f16 (x2048)
__global__ __launch_bounds__(256) void kred1(const float* __restrict__ P,
    const float* __restrict__ bias, float* __restrict__ feat_t,
    unsigned short* __restrict__ Fhi, unsigned short* __restrict__ Flo, int KS)
{
  int idx = blockIdx.x * 256 + threadIdx.x;
  if (idx >= NPOS * 512) return;
  int m = idx >> 9, n = idx & 511;
  int mt = m >> 7, ml = m & 127, nt = n >> 7, nl = n & 127;
  float s = 0.f;
  for (int z = 0; z < KS; ++z)
    s += P[(((size_t)(z * 20 + mt) * 4 + nt) << 14) + ml * 128 + nl];
  s += bias[n];
  feat_t[idx] = s;
  float fs = s * 2048.f;
  _Float16 hi = (_Float16)fs;
  _Float16 lo = (_Float16)(fs - (float)hi);
  ((_Float16*)Fhi)[idx] = hi;
  ((_Float16*)Flo)[idx] = lo;
}

// ============ K2: RPN split-f16 MFMA GEMM ============
__global__ __launch_bounds__(256) void k2_mfma(
    const unsigned short* __restrict__ Fhi, const unsigned short* __restrict__ Flo,
    const unsigned short* __restrict__ Whi, const unsigned short* __restrict__ Wlo,
    float* __restrict__ partial)
{
  __shared__ __align__(16) unsigned short As[8 * 162 * 8];
  __shared__ __align__(16) unsigned short Bs[8 * 130 * 8];
  int tid = threadIdx.x;
  int lane = tid & 63, wn = tid >> 6;
  int nt = blockIdx.x, mt = blockIdx.y, z = blockIdx.z;
  int n0 = nt * 128;

  f32x4 acc[10][2];
#pragma unroll
  for (int i = 0; i < 10; ++i)
#pragma unroll
    for (int j = 0; j < 2; ++j) acc[i][j] = (f32x4){0.f, 0.f, 0.f, 0.f};

  int yv[5], xv[5], slotA[5], gof[5];
  bool okv[5];
#pragma unroll
  for (int j = 0; j < 5; ++j) {
    int o = j * 256 + tid;
    int m = o >> 3, g = o & 7;
    int gm = mt * 160 + m;
    okv[j] = gm < NPOS;
    yv[j] = gm / 50;
    xv[j] = gm - yv[j] * 50;
    slotA[j] = g * 162 + m;
    gof[j] = g * 8;
  }

  ushort8 aR[5], bR[4];

  auto LOAD = [&](int t) {
    int tg = z * 27 + t;
    const unsigned short* Asrc = (tg < 144) ? Fhi : Flo;
    const unsigned short* Bsrc = (tg < 72 || tg >= 144) ? Whi : Wlo;
    int ks = (tg >= 144) ? (tg - 144) : ((tg >= 72) ? (tg - 72) : tg);
    int ki = ks * 64;
    int srow = ki >> 9;
    int c0 = ki & 511;
    int dy = srow / 3, dx = srow - (srow / 3) * 3;
#pragma unroll
    for (int j = 0; j < 5; ++j) {
      int yy = yv[j] + dy - 1, xx = xv[j] + dx - 1;
      ushort8 v = {0, 0, 0, 0, 0, 0, 0, 0};
      if (okv[j] && (unsigned)yy < 50u && (unsigned)xx < 50u)
        v = *(const ushort8*)(Asrc + (size_t)(yy * 50 + xx) * 512 + c0 + gof[j]);
      aR[j] = v;
    }
#pragma unroll
    for (int j = 0; j < 4; ++j) {
      int o = j * 256 + tid;
      int n = o >> 3, g = o & 7;
      bR[j] = *(const ushort8*)(Bsrc + (size_t)(n0 + n) * 4608 + ki + g * 8);
    }
  };

  LOAD(0);
  for (int t = 0; t < 27; ++t) {
    __syncthreads();
#pragma unroll
    for (int j = 0; j < 5; ++j)
      ((ushort8*)As)[slotA[j]] = aR[j];
#pragma unroll
    for (int j = 0; j < 4; ++j) {
      int o = j * 256 + tid;
      ((ushort8*)Bs)[(o & 7) * 130 + (o >> 3)] = bR[j];
    }
    __syncthreads();
    if (t + 1 < 27) LOAD(t + 1);
#pragma unroll
    for (int kk = 0; kk < 2; ++kk) {
      int g = kk * 4 + (lane >> 4);
      half8 b0 = ((const half8*)Bs)[g * 130 + wn * 32 + (lane & 15)];
      half8 b1 = ((const half8*)Bs)[g * 130 + wn * 32 + 16 + (lane & 15)];
#pragma unroll
      for (int fm = 0; fm < 10; ++fm) {
        half8 a = ((const half8*)As)[g * 162 + fm * 16 + (lane & 15)];
        acc[fm][0] = __builtin_amdgcn_mfma_f32_16x16x32_f16(a, b0, acc[fm][0], 0, 0, 0);
        acc[fm][1] = __builtin_amdgcn_mfma_f32_16x16x32_f16(a, b1, acc[fm][1], 0, 0, 0);
      }
    }
  }
  float* P = partial + ((size_t)(z * 16 + mt) * 4 + nt) * 20480;
#pragma unroll
  for (int fm = 0; fm < 10; ++fm)
#pragma unroll
    for (int fn = 0; fn < 2; ++fn)
#pragma unroll
      for (int r = 0; r < 4; ++r) {
        int m = fm * 16 + (lane >> 4) * 4 + r;
        int n = wn * 32 + fn * 16 + (lane & 15);
        P[m * 128 + n] = acc[fm][fn][r];
      }
}

// ---------------- K3 (fused): reduce k2 partials (/2^21) + bias/ReLU + heads + keys + hist ----------------
__global__ __launch_bounds__(256) void k3_fused(const float* __restrict__ P,
    const float* __restrict__ b_rpn,
    const float* __restrict__ w_score, const float* __restrict__ b_score,
    const float* __restrict__ w_delta, const float* __restrict__ b_delta,
    float4* __restrict__ boxes, u64* __restrict__ keys, int* __restrict__ hist)
{
  __shared__ float4 hv4[4][128];
  __shared__ float outv[4][54];
  int grp = threadIdx.x >> 6, lane = threadIdx.x & 63;
  int p = blockIdx.x * 4 + grp;
  int mt = p / 160, ml = p - mt * 160;
  int nt = lane >> 4;
  int nl8 = (lane * 8) & 127;

  float4 a0 = make_float4(0.f, 0.f, 0.f, 0.f);
  float4 a1 = make_float4(0.f, 0.f, 0.f, 0.f);
  for (int z = 0; z < 8; ++z) {
    const float* Pb = P + ((size_t)(z * 16 + mt) * 4 + nt) * 20480 + ml * 128 + nl8;
    float4 v0 = *(const float4*)Pb;
    float4 v1 = *(const float4*)(Pb + 4);
    a0.x += v0.x; a0.y += v0.y; a0.z += v0.z; a0.w += v0.w;
    a1.x += v1.x; a1.y += v1.y; a1.z += v1.z; a1.w += v1.w;
  }
  const float SC = 1.f / 2097152.f;
  const float4 b0 = *(const float4*)(b_rpn + lane * 8);
  const float4 b1 = *(const float4*)(b_rpn + lane * 8 + 4);
  float4 h0 = make_float4(fmaxf(a0.x * SC + b0.x, 0.f), fmaxf(a0.y * SC + b0.y, 0.f),
                          fmaxf(a0.z * SC + b0.z, 0.f), fmaxf(a0.w * SC + b0.w, 0.f));
  float4 h1 = make_float4(fmaxf(a1.x * SC + b1.x, 0.f), fmaxf(a1.y * SC + b1.y, 0.f),
                          fmaxf(a1.z * SC + b1.z, 0.f), fmaxf(a1.w * SC + b1.w, 0.f));
  hv4[grp][lane * 2] = h0;
  hv4[grp][lane * 2 + 1] = h1;
  __syncthreads();

  if (lane < 54) {
    const float* w; float bb;
    if (lane < 18) { w = w_score + lane * 512; bb = b_score[lane]; }
    else           { w = w_delta + (lane - 18) * 512; bb = b_delta[lane - 18]; }
    const float4* w4 = (const float4*)w;
    float s = 0.f;
#pragma unroll 4
    for (int q = 0; q < 128; ++q) {
      float4 a = hv4[grp][q], b = w4[q];
      s += a.x * b.x + a.y * b.y + a.z * b.z + a.w * b.w;
    }
    outv[grp][lane] = s + bb;
  }
  __syncthreads();
  if (lane < 9) {
    int k = lane;
    float s0 = outv[grp][2 * k], s1 = outv[grp][2 * k + 1];
    float mx = fmaxf(s0, s1);
    float e0 = expf(s0 - mx), e1 = expf(s1 - mx);
    float f = e1 / (e0 + e1);
    double ratio = (k < 3) ? 0.5 : ((k < 6) ? 1.0 : 2.0);
    int si = k - (k / 3) * 3;
    double scale = (si == 0) ? 8.0 : ((si == 1) ? 16.0 : 32.0);
    double sq = sqrt(ratio);
    double wsd = 16.0 * scale / sq;
    double hsd = 16.0 * scale * sq;
    int y = p / 50, x = p - (p / 50) * 50;
    double cxd = ((double)x + 0.5) * 16.0;
    double cyd = ((double)y + 0.5) * 16.0;
    float ax1 = (float)(cxd - wsd / 2.0);
    float ay1 = (float)(cyd - hsd / 2.0);
    float ax2 = (float)(cxd + wsd / 2.0);
    float ay2 = (float)(cyd + hsd / 2.0);
    float aw = ax2 - ax1, ah = ay2 - ay1;
    float axc = ax1 + aw * 0.5f, ayc = ay1 + ah * 0.5f;
    float d0 = outv[grp][18 + 4 * k], d1 = outv[grp][18 + 4 * k + 1];
    float d2 = outv[grp][18 + 4 * k + 2], d3 = outv[grp][18 + 4 * k + 3];
    float cx = axc + d0 * aw, cy = ayc + d1 * ah;
    float bw = aw * expf(d2), bh = ah * expf(d3);
    float bx1 = fminf(fmaxf(cx - bw * 0.5f, 0.f), 800.f);
    float by1 = fminf(fmaxf(cy - bh * 0.5f, 0.f), 800.f);
    float bx2 = fminf(fmaxf(cx + bw * 0.5f, 0.f), 800.f);
    float by2 = fminf(fmaxf(cy + bh * 0.5f, 0.f), 800.f);
    int idx = p * 9 + k;
    boxes[idx] = make_float4(bx1, by1, bx2, by2);
    u64 key = ((u64)__float_as_uint(f) << 32) | (u64)(0xFFFFFFFFu - (unsigned)idx);
    keys[idx] = key;
    atomicAdd(&hist[(unsigned)(key >> 46)], 1);
  }
}

// ============ K4 scan ============
__global__ __launch_bounds__(1024) void k4_scan(const int* __restrict__ hist,
    int* __restrict__ cur, int* __restrict__ nbig, int* __restrict__ wl)
{
  __shared__ int ps[1024];
  int t = threadIdx.x;
  int local[64];
  int s = 0;
#pragma unroll
  for (int j = 0; j < 64; ++j) { local[j] = hist[t * 64 + j]; s += local[j]; }
  int mysum = s;
  ps[t] = s;
  __syncthreads();
  for (int d = 1; d < 1024; d <<= 1) {
    int v = ps[t];
    int u = (t >= d) ? ps[t - d] : 0;
    __syncthreads();
    ps[t] = v + u;
    __syncthreads();
  }
  int base = ps[t] - mysum;
#pragma unroll
  for (int j = 0; j < 64; ++j) {
    int b = t * 64 + j;
    cur[b] = base;
    if (local[j] > THRESH) { int w = atomicAdd(nbig, 1); wl[w] = b; }
    base += local[j];
  }
}

// ============ K4 scatter: wave-aggregated atomics ============
__global__ __launch_bounds__(256) void k4_scatter(const u64* __restrict__ keys,
    int* __restrict__ cur, u64* __restrict__ membuf)
{
  int i = blockIdx.x * 256 + threadIdx.x;
  int lane = threadIdx.x & 63;
  bool valid = i < NA;
  u64 k = valid ? keys[i] : 0ull;
  unsigned b = (unsigned)(k >> 46);
  int pos = 0;
  u64 mask = __ballot(valid);
  while (mask) {
    int lead = __builtin_ctzll(mask);
    unsigned lb = (unsigned)__shfl((int)b, lead);
    u64 same = __ballot(valid && b == lb) & mask;
    int cnt = __popcll(same);
    int base = 0;
    if (lane == lead) base = atomicAdd(&cur[lb], cnt);
    base = __shfl(base, lead);
    if (valid && ((same >> lane) & 1ull)) {
      int rank = __popcll(same & ((1ull << lane) - 1ull));
      pos = base + rank;
    }
    mask &= ~same;
  }
  if (valid) membuf[pos] = k;
}

// ============ K4 select (REP) ============
__global__ __launch_bounds__(1024) void k4_select(const u64* __restrict__ keys,
    const int* __restrict__ hist, const int* __restrict__ cur,
    const int* __restrict__ nbig, const int* __restrict__ wl,
    const u64* __restrict__ membuf, u64* __restrict__ membuf2,
    const float4* __restrict__ boxes, float4* __restrict__ cand,
    float* __restrict__ areas)
{
  __shared__ int cnt[NSUB];
  __shared__ int cur2[NSUB];
  __shared__ int ps[1024];
  int t = threadIdx.x;
  if (blockIdx.x < RANKBLKS) {
    int i = blockIdx.x * 1024 + t;
    for (int rep = 0; rep < REP_K4S; ++rep) {
      if (i < NA) {
        u64 my = keys[i];
        unsigned b = (unsigned)(my >> 46);
        int cb = hist[b];
        if (cb <= THRESH) {
          int hi = cur[b];
          int lo = hi - cb;
          int r = NA - hi;
          for (int p = lo; p < hi; ++p) r += (membuf[p] > my) ? 1 : 0;
          if (r < TOPN) {
            unsigned idx = 0xFFFFFFFFu - (unsigned)my;
            float4 bx = boxes[idx];
            cand[r] = bx;
            areas[r] = (bx.z - bx.x) * (bx.w - bx.y);
          }
        }
      }
    }
    return;
  }
  int nb = *nbig;
  for (int rep = 0; rep < REP_K4S; ++rep) {
  for (int wi = blockIdx.x - RANKBLKS; wi < nb; wi += gridDim.x - RANKBLKS) {
    int b = wl[wi];
    int hi = cur[b], S = hist[b], lo = hi - S;
    for (int j = t; j < NSUB; j += 1024) cnt[j] = 0;
    __syncthreads();
    for (int e = lo + t; e < hi; e += 1024)
      atomicAdd(&cnt[(unsigned)(membuf[e] >> 33) & (NSUB - 1)], 1);
    __syncthreads();
    int loc[8], s = 0;
#pragma unroll
    for (int j = 0; j < 8; ++j) { loc[j] = cnt[t * 8 + j]; s += loc[j]; }
    ps[t] = s;
    __syncthreads();
    for (int d = 1; d < 1024; d <<= 1) {
      int v = ps[t];
      int u = (t >= d) ? ps[t - d] : 0;
      __syncthreads();
      ps[t] = v + u;
      __syncthreads();
    }
    int run = ps[1023] - ps[t];
#pragma unroll
    for (int j = 7; j >= 0; --j) {
      cur2[t * 8 + j] = lo + run;
      run += loc[j];
    }
    __syncthreads();
    for (int e = lo + t; e < hi; e += 1024) {
      u64 k = membuf[e];
      int p = atomicAdd(&cur2[(unsigned)(k >> 33) & (NSUB - 1)], 1);
      membuf2[p] = k;
    }
    __syncthreads();
    for (int e = lo + t; e < hi; e += 1024) {
      u64 my = membuf2[e];
      unsigned b2 = (unsigned)(my >> 33) & (NSUB - 1);
      int end = cur2[b2], start = end - cnt[b2];
      int r = (NA - hi) + (start - lo);
      for (int p = start; p < end; ++p) r += (membuf2[p] > my) ? 1 : 0;
      if (r < TOPN) {
        unsigned idx = 0xFFFFFFFFu - (unsigned)my;
        float4 bx = boxes[idx];
        cand[r] = bx;
        areas[r] = (bx.z - bx.x) * (bx.w - bx.y);
      }
    }
    __syncthreads();
  }
  }  // rep
}

// ---------------- K5 (REP): IoU > 0.7 bit matrix ----------------
__global__ __launch_bounds__(256) void k5_iou(const float4* __restrict__ cand,
    const float* __restrict__ areas, u64* __restrict__ rowbuf)
{
  __shared__ float4 bj[64];
  __shared__ float aj[64];
  int jw = blockIdx.x;
  int i = blockIdx.y * 256 + threadIdx.x;
  if (threadIdx.x < 64) {
    int j = jw * 64 + threadIdx.x;
    bj[threadIdx.x] = (j < TOPN) ? cand[j] : make_float4(0.f, 0.f, 0.f, 0.f);
    aj[threadIdx.x] = (j < TOPN) ? areas[j] : 0.f;
  }
  __syncthreads();
  for (int rep = 0; rep < REP_K5; ++rep) {
    if (i < TOPN) {
      u64 word = 0ull;
      if (jw * 64 + 63 > i) {
        float4 bi = cand[i];
        float ai = areas[i];
#pragma unroll 8
        for (int b = 0; b < 64; ++b) {
          float4 bb = bj[b];
          float lx = fmaxf(bi.x, bb.x), ly = fmaxf(bi.y, bb.y);
          float rx = fminf(bi.z, bb.z), ry = fminf(bi.w, bb.w);
          float ww = fmaxf(rx - lx, 0.f), hh = fmaxf(ry - ly, 0.f);
          float inter = ww * hh;
          float iou = inter / (ai + aj[b] - inter + 1e-9f);
          int j = jw * 64 + b;
          if (iou > 0.7f && j > i && j < TOPN) word |= 1ull << b;
        }
      }
      rowbuf[(size_t)i * 96 + jw] = word;
    }
  }
}

// ---------------- K6: greedy NMS scan ----------------
__global__ __launch_bounds__(256) void k6_scan(const u64* __restrict__ rowbuf,
    const float4* __restrict__ cand, float4* __restrict__ rois)
{
  __shared__ u64 stage[64 * 97];
  __shared__ u64 sup[94];
  __shared__ int prefS[94];
  __shared__ int baseU_sh;
  int tid = threadIdx.x;
  if (tid < 94) sup[tid] = 0ull;
  if (tid == 0) baseU_sh = 0;

  u64 pre[24];
#pragma unroll
  for (int j = 0; j < 24; ++j) {
    int o = j * 256 + tid;
    int b = o / 94, w = o - b * 94;
    pre[j] = (o < 6016) ? rowbuf[(size_t)b * 96 + w] : 0ull;
  }
  __syncthreads();

  for (int c = 0; c < 94; ++c) {
#pragma unroll
    for (int j = 0; j < 24; ++j) {
      int o = j * 256 + tid;
      int b = o / 94, w = o - b * 94;
      if (o < 6016) stage[b * 97 + w] = pre[j];
    }
    __syncthreads();
    if (c + 1 < 94) {
#pragma unroll
      for (int j = 0; j < 24; ++j) {
        int o = j * 256 + tid;
        int b = o / 94, w = o - b * 94;
        pre[j] = (o < 6016) ? rowbuf[((size_t)(c + 1) * 64 + b) * 96 + w] : 0ull;
      }
    }
    u64 valid = (c == 93) ? ((1ull << 48) - 1ull) : ~0ull;
    u64 sup_c = sup[c];
    u64 live0 = ~sup_c & valid;
    u64 rw = stage[(tid & 63) * 97 + c];
    u64 live = live0, keep = 0ull;
    while (live) {
      int b = __builtin_ctzll(live);
      keep |= 1ull << b;
      u64 rb = (u64)__shfl((long long)rw, b);
      live &= ~rb;
      live &= ~(1ull << b);
    }
    int baseU = baseU_sh;
    if (tid < 64 && ((keep >> tid) & 1ull)) {
      u64 below = (tid == 0) ? 0ull : (keep & ((1ull << tid) - 1ull));
      int pos = baseU + __popcll(below);
      if (pos < NKEEP) rois[pos] = cand[c * 64 + tid];
    }
    __syncthreads();
    if (tid == 0) baseU_sh = baseU + __popcll(keep);
    if (tid == 64) sup[c] = sup_c | (live0 & ~keep);
    for (int w = c + 1 + tid; w < 94; w += 256) {
      u64 a = sup[w];
      u64 kk = keep;
      while (kk) {
        int b = __builtin_ctzll(kk);
        kk &= kk - 1;
        a |= stage[b * 97 + w];
      }
      sup[w] = a;
    }
    __syncthreads();
    if (baseU_sh >= NKEEP) break;
  }

  int totU = baseU_sh;
  if (totU < NKEEP) {
    if (tid == 0) {
      int s = 0;
      for (int w = 0; w < 94; ++w) { prefS[w] = s; s += __popcll(sup[w]); }
    }
    __syncthreads();
    for (int i = tid; i < TOPN; i += 256) {
      int w = i >> 6, b = i & 63;
      u64 sw = sup[w];
      if ((sw >> b) & 1ull) {
        u64 below = (b == 0) ? 0ull : (sw & ((1ull << b) - 1ull));
        int pos = totU + prefS[w] + __popcll(below);
        if (pos < NKEEP) rois[pos] = cand[i];
      }
    }
  }
}

// ---------------- K7 (REP): roi_align -> pool bf16 in k8's LDS layout ----------------
__global__ __launch_bounds__(256) void k7_roi(const float4* __restrict__ rois,
    const float* __restrict__ feat_t, unsigned short* __restrict__ pool_bf)
{
  int r = blockIdx.x;
  int py = blockIdx.y / 7, px = blockIdx.y - (blockIdx.y / 7) * 7;
  int c = threadIdx.x;
  bool rok = r < NKEEP;
  for (int rep = 0; rep < REP_K7; ++rep) {
  float4 box = rok ? rois[r] : make_float4(0.f, 0.f, 0.f, 0.f);
  float x1 = box.x * 0.0625f, y1 = box.y * 0.0625f;
  float x2 = box.z * 0.0625f, y2 = box.w * 0.0625f;
  float acc0 = 0.f, acc1 = 0.f;
#pragma unroll
  for (int sy = 0; sy < 2; ++sy) {
#pragma unroll
    for (int sx = 0; sx < 2; ++sx) {
      float offx = ((float)(2 * px + sx) + 0.5f) * 0.5f;
      float offy = ((float)(2 * py + sy) + 0.5f) * 0.5f;
      float xs = x1 + (offx * (x2 - x1)) / 7.f;
      float ys = y1 + (offy * (y2 - y1)) / 7.f;
      float x0f = floorf(xs), y0f = floorf(ys);
      float lx = xs - x0f, ly = ys - y0f;
      int x0i = (int)fminf(fmaxf(x0f, 0.f), 49.f);
      int x1i = (int)fminf(fmaxf(x0f + 1.f, 0.f), 49.f);
      int y0i = (int)fminf(fmaxf(y0f, 0.f), 49.f);
      int y1i = (int)fminf(fmaxf(y0f + 1.f, 0.f), 49.f);
      const float* f00 = feat_t + (size_t)(y0i * 50 + x0i) * 512;
      const float* f01 = feat_t + (size_t)(y0i * 50 + x1i) * 512;
      const float* f10 = feat_t + (size_t)(y1i * 50 + x0i) * 512;
      const float* f11 = feat_t + (size_t)(y1i * 50 + x1i) * 512;
      float w00 = (1.f - ly) * (1.f - lx), w01 = (1.f - ly) * lx;
      float w10 = ly * (1.f - lx),          w11 = ly * lx;
      acc0 += w00 * f00[c] + w01 * f01[c] + w10 * f10[c] + w11 * f11[c];
      acc1 += w00 * f00[c + 256] + w01 * f01[c + 256] + w10 * f10[c + 256] + w11 * f11[c + 256];
    }
  }
  int k0 = c * 49 + py * 7 + px;
  int k1v = (c + 256) * 49 + py * 7 + px;
  unsigned short v0 = rok ? f2bf(acc0 * 0.25f) : (unsigned short)0;
  unsigned short v1 = rok ? f2bf(acc1 * 0.25f) : (unsigned short)0;
  pool_bf[(k0 >> 6) * 20480 + (((k0 >> 3) & 7) * 320 + r) * 8 + (k0 & 7)] = v0;
  pool_bf[(k1v >> 6) * 20480 + (((k1v >> 3) & 7) * 320 + r) * 8 + (k1v & 7)] = v1;
  }  // rep
}

// ---------------- K8 (REP): fc7 GEMM bf16 MFMA, streaming W ----------------
__global__ __launch_bounds__(512) void k8_gemm(const unsigned short* __restrict__ Ap,
    const float* __restrict__ W, float* __restrict__ partial, int spk)
{
  __shared__ __align__(16) unsigned short As[8 * 320 * 8];
  __shared__ __align__(16) unsigned short Bs[8 * 128 * 8];
  int tid = threadIdx.x;
  int lane = tid & 63, wv = tid >> 6;
  int wm = wv & 1, wn = wv >> 1;
  int n0 = blockIdx.x * 128;
  int by = blockIdx.y;
  int steps = min(spk, KSTEPS - by * spk);

  ushort8 aReg[5];
  float4 wReg[4];

  auto LOAD = [&](int t) {
    size_t abase = (size_t)(by * spk + t) * 20480;
    int k0 = (by * spk + t) * 64;
#pragma unroll
    for (int j = 0; j < 5; ++j)
      aReg[j] = *(const ushort8*)(Ap + abase + (size_t)(j * 512 + tid) * 8);
#pragma unroll
    for (int j = 0; j < 4; ++j) {
      int fq = j * 512 + tid;
      int n = fq >> 4, kq = fq & 15;
      wReg[j] = *(const float4*)(W + (size_t)(n0 + n) * 25088 + k0 + kq * 4);
    }
  };

  f32x4 acc[10][2];
  for (int rep = 0; rep < REP_K8; ++rep) {
#pragma unroll
  for (int i = 0; i < 10; ++i)
#pragma unroll
    for (int j = 0; j < 2; ++j) acc[i][j] = (f32x4){0.f, 0.f, 0.f, 0.f};

  LOAD(0);
  for (int t = 0; t < steps; ++t) {
    u64 pk[4];
#pragma unroll
    for (int j = 0; j < 4; ++j) {
      float4 v = wReg[j];
      pk[j] = (u64)f2bf(v.x) | ((u64)f2bf(v.y) << 16)
            | ((u64)f2bf(v.z) << 32) | ((u64)f2bf(v.w) << 48);
    }
    __syncthreads();
#pragma unroll
    for (int j = 0; j < 5; ++j)
      ((ushort8*)As)[j * 512 + tid] = aReg[j];
#pragma unroll
    for (int j = 0; j < 4; ++j) {
      int fq = j * 512 + tid;
      int n = fq >> 4, kq = fq & 15;
      *(u64*)&Bs[((kq >> 1) * 128 + n) * 8 + (kq & 1) * 4] = pk[j];
    }
    __syncthreads();
    if (t + 1 < steps) LOAD(t + 1);
#pragma unroll
    for (int kk = 0; kk < 2; ++kk) {
      int g = kk * 4 + (lane >> 4);
      short8 b0 = ((const short8*)Bs)[g * 128 + wn * 32 + (lane & 15)];
      short8 b1 = ((const short8*)Bs)[g * 128 + wn * 32 + 16 + (lane & 15)];
#pragma unroll
      for (int fm = 0; fm < 10; ++fm) {
        short8 a = ((const short8*)As)[g * 320 + wm * 160 + fm * 16 + (lane & 15)];
        acc[fm][0] = __builtin_amdgcn_mfma_f32_16x16x32_bf16(a, b0, acc[fm][0], 0, 0, 0);
        acc[fm][1] = __builtin_amdgcn_mfma_f32_16x16x32_bf16(a, b1, acc[fm][1], 0, 0, 0);
      }
    }
  }
  }  // rep
  float* P = partial + (size_t)(by * 32 + blockIdx.x) * (320 * 128);
#pragma unroll
  for (int fm = 0; fm < 10; ++fm)
#pragma unroll
    for (int fn = 0; fn < 2; ++fn)
#pragma unroll
      for (int r = 0; r < 4; ++r) {
        int m = wm * 160 + fm * 16 + (lane >> 4) * 4 + r;
        int n = wn * 32 + fn * 16 + (lane & 15);
        P[m * 128 + n] = acc[fm][fn][r];
      }
}

// ---------------- K9a (REP): reduce k8 partials -> fc7 f32 (+bias/ReLU) ----------------
__global__ __launch_bounds__(256) void k9a_reduce(const float* __restrict__ partial,
    const float* __restrict__ bias, float* __restrict__ fc7, int KS)
{
  int idx = blockIdx.x * 256 + threadIdx.x;
  if (idx >= 300 * 4096) return;
  int m = idx >> 12, n = idx & 4095;
  int nt = n >> 7, nn = n & 127;
  for (int rep = 0; rep < REP_K9A; ++rep) {
    float s = 0.f;
    for (int ks = 0; ks < KS; ++ks)
      s += partial[((size_t)(ks * 32 + nt) * 320 + m) * 128 + nn];
    s += bias[n];
    fc7[idx] = fmaxf(s, 0.f);
  }
}

// ---------------- K9b (REP): cls/reg heads, one wave per (m, o) dot product ----------------
__global__ __launch_bounds__(256) void k9b_heads(const float* __restrict__ fc7,
    const float* __restrict__ wc, const float* __restrict__ bc,
    const float* __restrict__ wr, const float* __restrict__ br,
    float* __restrict__ out)
{
  int wid = blockIdx.x * 4 + (threadIdx.x >> 6);
  int lane = threadIdx.x & 63;
  if (wid >= 300 * 105) return;
  int m = wid / 105, o = wid - m * 105;
  const float* w; float b;
  if (o < 21) { w = wc + (size_t)o * 4096; b = bc[o]; }
  else        { w = wr + (size_t)(o - 21) * 4096; b = br[o - 21]; }
  const float4* f4 = (const float4*)(fc7 + (size_t)m * 4096);
  const float4* w4 = (const float4*)w;
  for (int rep = 0; rep < REP_K9B; ++rep) {
    float s = 0.f;
#pragma unroll
    for (int i = 0; i < 16; ++i) {
      float4 a = f4[i * 64 + lane];
      float4 ww = w4[i * 64 + lane];
      s += a.x * ww.x + a.y * ww.y + a.z * ww.z + a.w * ww.w;
    }
#pragma unroll
    for (int d = 32; d > 0; d >>= 1) s += __shfl_down(s, d);
    if (lane == 0) {
      s += b;
      if (o < 21) out[m * 21 + o] = s;
      else        out[6300 + m * 84 + (o - 21)] = s;
    }
  }
}

extern "C" void kernel_launch(void* const* d_in, const int* in_sizes, int n_in,
                              void* d_out, int out_size, void* d_ws, size_t ws_size,
                              hipStream_t stream)
{
  (void)in_sizes; (void)n_in; (void)out_size;
  const float* img    = (const float*)d_in[0];
  const float* w_feat = (const float*)d_in[1];
  const float* b_feat = (const float*)d_in[2];
  const float* w_rpn  = (const float*)d_in[3];
  const float* b_rpn  = (const float*)d_in[4];
  const float* w_score= (const float*)d_in[5];
  const float* b_score= (const float*)d_in[6];
  const float* w_delta= (const float*)d_in[7];
  const float* b_delta= (const float*)d_in[8];
  const float* w_fc7  = (const float*)d_in[9];
  const float* b_fc7  = (const float*)d_in[10];
  const float* w_cls  = (const float*)d_in[11];
  const float* b_cls  = (const float*)d_in[12];
  const float* w_reg  = (const float*)d_in[13];
  const float* b_reg  = (const float*)d_in[14];
  float* out = (float*)d_out;

  char* ws = (char*)d_ws;
  size_t off = 0;
  auto alloc = [&](size_t bytes) -> void* {
    void* p = ws + off;
    off = (off + bytes + 511) & ~(size_t)511;
    return p;
  };
  float* feat_t  = (float*)alloc(5120000);
  unsigned short* Fhi = (unsigned short*)alloc((size_t)NPOS * 512 * 2);
  unsigned short* Flo = (unsigned short*)alloc((size_t)NPOS * 512 * 2);
  unsigned short* Whi = (unsigned short*)alloc((size_t)512 * 4608 * 2);
  unsigned short* Wlo = (unsigned short*)alloc((size_t)512 * 4608 * 2);
  float4* boxes  = (float4*)alloc((size_t)NA * 16);
  u64* keys      = (u64*)alloc((size_t)NA * 8);
  int* histbuf   = (int*)alloc((size_t)(NBUCK + 1 + 256) * 4);
  int* hist = histbuf; int* nbig = histbuf + NBUCK; int* wl = histbuf + NBUCK + 1;
  int* bcur      = (int*)alloc((size_t)NBUCK * 4);
  u64* membuf    = (u64*)alloc((size_t)NA * 8);
  u64* membuf2   = (u64*)alloc((size_t)NA * 8);
  float4* cand   = (float4*)alloc((size_t)TOPN * 16);
  float* areas   = (float*)alloc((size_t)TOPN * 4);
  u64* rowbuf    = (u64*)alloc((size_t)TOPN * 96 * 8);
  float4* rois   = (float4*)alloc(NKEEP * 16);
  unsigned short* pool_bf = (unsigned short*)alloc((size_t)KSTEPS * 20480 * 2);
  float* fc7     = (float*)alloc((size_t)300 * 4096 * 4);

  size_t avail = (ws_size > off) ? (ws_size - off) : 0;
  float* P_sh = (float*)(ws + off);
  int KS1 = 8, KS8 = 8;
  while (KS1 > 1 && (size_t)KS1 * 80 * 16384 * 4 > avail) KS1 >>= 1;
  while (KS8 > 1 && (size_t)KS8 * 32 * 320 * 128 * 4 > avail) KS8 >>= 1;
  int klen1 = 768 / KS1;
  int spk8 = (KSTEPS + KS8 - 1) / KS8;

  k1_gemm<<<dim3(20, 4, KS1), 256, 0, stream>>>(img, w_feat, P_sh, klen1,
                                                w_rpn, Whi, Wlo, histbuf);
  kred1<<<(NPOS * 512 + 255) / 256, 256, 0, stream>>>(P_sh, b_feat, feat_t, Fhi, Flo, KS1);
  k2_mfma<<<dim3(4, 16, 8), 256, 0, stream>>>(Fhi, Flo, Whi, Wlo, P_sh);
  k3_fused<<<625, 256, 0, stream>>>(P_sh, b_rpn, w_score, b_score, w_delta, b_delta,
                                    boxes, keys, hist);
  k4_scan   <<<1, 1024, 0, stream>>>(hist, bcur, nbig, wl);
  k4_scatter<<<88, 256, 0, stream>>>(keys, bcur, membuf);
  k4_select <<<RANKBLKS + 64, 1024, 0, stream>>>(keys, hist, bcur, nbig, wl,
                                                 membuf, membuf2, boxes, cand, areas);
  k5_iou    <<<dim3(94, 24), 256, 0, stream>>>(cand, areas, rowbuf);
  k6_scan   <<<1, 256, 0, stream>>>(rowbuf, cand, rois);
  k7_roi    <<<dim3(320, 49), 256, 0, stream>>>(rois, feat_t, pool_bf);
  k8_gemm   <<<dim3(32, KS8), 512, 0, stream>>>(pool_bf, w_fc7, P_sh, spk8);
  k9a_reduce<<<(300 * 4096 + 255) / 256, 256, 0, stream>>>(P_sh, b_fc7, fc7, KS8);
  k9b_heads<<<(300 * 105 + 3) / 4, 256, 0, stream>>>(fc7, w_cls, b_cls, w_reg, b_reg, out);
}

// Round 18
// 844.073 us; speedup vs baseline: 3.6436x; 3.6436x over previous
//
#include <hip/hip_runtime.h>
#include <cstdint>

typedef short  short8  __attribute__((ext_vector_type(8)));
typedef unsigned short ushort8 __attribute__((ext_vector_type(8)));
typedef _Float16 half8 __attribute__((ext_vector_type(8)));
typedef float  f32x4   __attribute__((ext_vector_type(4)));
typedef unsigned long long u64;

#define NPOS 2500
#define NA   22500
#define TOPN 6000
#define NKEEP 300
#define NBUCK 65536
#define THRESH 512
#define NSUB 8192
#define KSTEPS 392   // 25088 / 64
#define RANKBLKS 22  // ceil(22500/1024)

__device__ __forceinline__ unsigned short f2bf(float f) {
  unsigned u = __float_as_uint(f);
  return (unsigned short)((u + 0x7FFFu + ((u >> 16) & 1u)) >> 16);
}

// ============ KW: w_rpn transpose/split via LDS (coalesced both sides) + hist zero ============
__global__ __launch_bounds__(256) void kw_prep(const float* __restrict__ wr,
    unsigned short* __restrict__ Whi, unsigned short* __restrict__ Wlo,
    int* __restrict__ histbuf)
{
  __shared__ float wrow[4608];
  int n = blockIdx.x, tid = threadIdx.x;
  {
    int gtid = n * 256 + tid;
    if (gtid < NBUCK + 1 + 256) histbuf[gtid] = 0;
  }
  for (int i = tid; i < 4608; i += 256) wrow[i] = wr[(size_t)n * 4608 + i];
  __syncthreads();
  for (int o = tid; o < 4608; o += 256) {
    int s = o >> 9, c = o & 511;
    float w = wrow[c * 9 + s] * 1024.f;
    _Float16 hi = (_Float16)w;
    _Float16 lo = (_Float16)(w - (float)hi);
    ((_Float16*)Whi)[(size_t)n * 4608 + o] = hi;
    ((_Float16*)Wlo)[(size_t)n * 4608 + o] = lo;
  }
}

// ============ K1: patchify conv f32 GEMM (pure) ============
__global__ __launch_bounds__(256) void k1_gemm(const float* __restrict__ Asrc,
    const float* __restrict__ Bsrc, float* __restrict__ P, int klen)
{
  __shared__ float As[32][128];
  __shared__ float Bs[32][132];
  int tid = threadIdx.x;
  int tx = tid & 15, ty = tid >> 4;
  int mt = blockIdx.x, nt = blockIdx.y;
  int m0 = mt * 128, n0 = nt * 128;
  int kbase = blockIdx.z * klen;

  int m_loc = tid & 127;
  int half = tid >> 7;
  int gm = m0 + m_loc;
  int y = gm / 50, x = gm - y * 50;
  bool mok = gm < NPOS;

  float acc[8][8] = {};

  for (int kt = 0; kt < klen; kt += 32) {
    int kb = kbase + kt;
    int k0 = kb + half * 16;
    int ci = k0 >> 8, r = (k0 >> 4) & 15;
    const float* src = Asrc + ci * 640000 + (y * 16 + r) * 800 + x * 16;
#pragma unroll
    for (int j = 0; j < 4; ++j) {
      float4 v = mok ? *(const float4*)(src + j * 4) : make_float4(0.f, 0.f, 0.f, 0.f);
      As[half * 16 + j * 4 + 0][m_loc] = v.x;
      As[half * 16 + j * 4 + 1][m_loc] = v.y;
      As[half * 16 + j * 4 + 2][m_loc] = v.z;
      As[half * 16 + j * 4 + 3][m_loc] = v.w;
    }
#pragma unroll
    for (int i = 0; i < 4; ++i) {
      int e = i * 256 + tid;
      int k4 = e & 7, n = e >> 3;
      float4 v = *(const float4*)(Bsrc + (size_t)(n0 + n) * 768 + kb + k4 * 4);
      Bs[k4 * 4 + 0][n] = v.x;
      Bs[k4 * 4 + 1][n] = v.y;
      Bs[k4 * 4 + 2][n] = v.z;
      Bs[k4 * 4 + 3][n] = v.w;
    }
    __syncthreads();
#pragma unroll 8
    for (int k = 0; k < 32; ++k) {
      float4 a0 = *(const float4*)&As[k][ty * 8];
      float4 a1 = *(const float4*)&As[k][ty * 8 + 4];
      float4 b0 = *(const float4*)&Bs[k][tx * 8];
      float4 b1 = *(const float4*)&Bs[k][tx * 8 + 4];
      float av[8] = {a0.x, a0.y, a0.z, a0.w, a1.x, a1.y, a1.z, a1.w};
      float bv[8] = {b0.x, b0.y, b0.z, b0.w, b1.x, b1.y, b1.z, b1.w};
#pragma unroll
      for (int i2 = 0; i2 < 8; ++i2)
#pragma unroll
        for (int j2 = 0; j2 < 8; ++j2) acc[i2][j2] += av[i2] * bv[j2];
    }
    __syncthreads();
  }
  float* Pp = P + ((size_t)(blockIdx.z * 20 + mt) * 4 + nt) * 16384;
#pragma unroll
  for (int i = 0; i < 8; ++i) {
    float4 v0 = {acc[i][0], acc[i][1], acc[i][2], acc[i][3]};
    float4 v1 = {acc[i][4], acc[i][5], acc[i][6], acc[i][7]};
    *(float4*)&Pp[(ty * 8 + i) * 128 + tx * 8] = v0;
    *(float4*)&Pp[(ty * 8 + i) * 128 + tx * 8 + 4] = v1;
  }
}

// kred1: reduce k1 partials -> feat_t f32 + feat hi/lo f16 (x2048)
__global__ __launch_bounds__(256) void kred1(const float* __restrict__ P,
    const float* __restrict__ bias, float* __restrict__ feat_t,
    unsigned short* __restrict__ Fhi, unsigned short* __restrict__ Flo, int KS)
{
  int idx = blockIdx.x * 256 + threadIdx.x;
  if (idx >= NPOS * 512) return;
  int m = idx >> 9, n = idx & 511;
  int mt = m >> 7, ml = m & 127, nt = n >> 7, nl = n & 127;
  float s = 0.f;
  for (int z = 0; z < KS; ++z)
    s += P[(((size_t)(z * 20 + mt) * 4 + nt) << 14) + ml * 128 + nl];
  s += bias[n];
  feat_t[idx] = s;
  float fs = s * 2048.f;
  _Float16 hi = (_Float16)fs;
  _Float16 lo = (_Float16)(fs - (float)hi);
  ((_Float16*)Fhi)[idx] = hi;
  ((_Float16*)Flo)[idx] = lo;
}

// ============ K2: RPN split-f16 MFMA GEMM ============
__global__ __launch_bounds__(256) void k2_mfma(
    const unsigned short* __restrict__ Fhi, const unsigned short* __restrict__ Flo,
    const unsigned short* __restrict__ Whi, const unsigned short* __restrict__ Wlo,
    float* __restrict__ partial)
{
  __shared__ __align__(16) unsigned short As[8 * 162 * 8];
  __shared__ __align__(16) unsigned short Bs[8 * 130 * 8];
  int tid = threadIdx.x;
  int lane = tid & 63, wn = tid >> 6;
  int nt = blockIdx.x, mt = blockIdx.y, z = blockIdx.z;
  int n0 = nt * 128;

  f32x4 acc[10][2];
#pragma unroll
  for (int i = 0; i < 10; ++i)
#pragma unroll
    for (int j = 0; j < 2; ++j) acc[i][j] = (f32x4){0.f, 0.f, 0.f, 0.f};

  int yv[5], xv[5], slotA[5], gof[5];
  bool okv[5];
#pragma unroll
  for (int j = 0; j < 5; ++j) {
    int o = j * 256 + tid;
    int m = o >> 3, g = o & 7;
    int gm = mt * 160 + m;
    okv[j] = gm < NPOS;
    yv[j] = gm / 50;
    xv[j] = gm - yv[j] * 50;
    slotA[j] = g * 162 + m;
    gof[j] = g * 8;
  }

  ushort8 aR[5], bR[4];

  auto LOAD = [&](int t) {
    int tg = z * 27 + t;
    const unsigned short* Asrc = (tg < 144) ? Fhi : Flo;
    const unsigned short* Bsrc = (tg < 72 || tg >= 144) ? Whi : Wlo;
    int ks = (tg >= 144) ? (tg - 144) : ((tg >= 72) ? (tg - 72) : tg);
    int ki = ks * 64;
    int srow = ki >> 9;
    int c0 = ki & 511;
    int dy = srow / 3, dx = srow - (srow / 3) * 3;
#pragma unroll
    for (int j = 0; j < 5; ++j) {
      int yy = yv[j] + dy - 1, xx = xv[j] + dx - 1;
      ushort8 v = {0, 0, 0, 0, 0, 0, 0, 0};
      if (okv[j] && (unsigned)yy < 50u && (unsigned)xx < 50u)
        v = *(const ushort8*)(Asrc + (size_t)(yy * 50 + xx) * 512 + c0 + gof[j]);
      aR[j] = v;
    }
#pragma unroll
    for (int j = 0; j < 4; ++j) {
      int o = j * 256 + tid;
      int n = o >> 3, g = o & 7;
      bR[j] = *(const ushort8*)(Bsrc + (size_t)(n0 + n) * 4608 + ki + g * 8);
    }
  };

  LOAD(0);
  for (int t = 0; t < 27; ++t) {
    __syncthreads();
#pragma unroll
    for (int j = 0; j < 5; ++j)
      ((ushort8*)As)[slotA[j]] = aR[j];
#pragma unroll
    for (int j = 0; j < 4; ++j) {
      int o = j * 256 + tid;
      ((ushort8*)Bs)[(o & 7) * 130 + (o >> 3)] = bR[j];
    }
    __syncthreads();
    if (t + 1 < 27) LOAD(t + 1);
#pragma unroll
    for (int kk = 0; kk < 2; ++kk) {
      int g = kk * 4 + (lane >> 4);
      half8 b0 = ((const half8*)Bs)[g * 130 + wn * 32 + (lane & 15)];
      half8 b1 = ((const half8*)Bs)[g * 130 + wn * 32 + 16 + (lane & 15)];
#pragma unroll
      for (int fm = 0; fm < 10; ++fm) {
        half8 a = ((const half8*)As)[g * 162 + fm * 16 + (lane & 15)];
        acc[fm][0] = __builtin_amdgcn_mfma_f32_16x16x32_f16(a, b0, acc[fm][0], 0, 0, 0);
        acc[fm][1] = __builtin_amdgcn_mfma_f32_16x16x32_f16(a, b1, acc[fm][1], 0, 0, 0);
      }
    }
  }
  float* P = partial + ((size_t)(z * 16 + mt) * 4 + nt) * 20480;
#pragma unroll
  for (int fm = 0; fm < 10; ++fm)
#pragma unroll
    for (int fn = 0; fn < 2; ++fn)
#pragma unroll
      for (int r = 0; r < 4; ++r) {
        int m = fm * 16 + (lane >> 4) * 4 + r;
        int n = wn * 32 + fn * 16 + (lane & 15);
        P[m * 128 + n] = acc[fm][fn][r];
      }
}

// ---------------- K3 (fused): reduce k2 partials (/2^21) + bias/ReLU + heads + keys + hist ----------------
__global__ __launch_bounds__(256) void k3_fused(const float* __restrict__ P,
    const float* __restrict__ b_rpn,
    const float* __restrict__ w_score, const float* __restrict__ b_score,
    const float* __restrict__ w_delta, const float* __restrict__ b_delta,
    float4* __restrict__ boxes, u64* __restrict__ keys, int* __restrict__ hist)
{
  __shared__ float4 hv4[4][128];
  __shared__ float outv[4][54];
  int grp = threadIdx.x >> 6, lane = threadIdx.x & 63;
  int p = blockIdx.x * 4 + grp;
  int mt = p / 160, ml = p - mt * 160;
  int nt = lane >> 4;
  int nl8 = (lane * 8) & 127;

  float4 a0 = make_float4(0.f, 0.f, 0.f, 0.f);
  float4 a1 = make_float4(0.f, 0.f, 0.f, 0.f);
  for (int z = 0; z < 8; ++z) {
    const float* Pb = P + ((size_t)(z * 16 + mt) * 4 + nt) * 20480 + ml * 128 + nl8;
    float4 v0 = *(const float4*)Pb;
    float4 v1 = *(const float4*)(Pb + 4);
    a0.x += v0.x; a0.y += v0.y; a0.z += v0.z; a0.w += v0.w;
    a1.x += v1.x; a1.y += v1.y; a1.z += v1.z; a1.w += v1.w;
  }
  const float SC = 1.f / 2097152.f;
  const float4 b0 = *(const float4*)(b_rpn + lane * 8);
  const float4 b1 = *(const float4*)(b_rpn + lane * 8 + 4);
  float4 h0 = make_float4(fmaxf(a0.x * SC + b0.x, 0.f), fmaxf(a0.y * SC + b0.y, 0.f),
                          fmaxf(a0.z * SC + b0.z, 0.f), fmaxf(a0.w * SC + b0.w, 0.f));
  float4 h1 = make_float4(fmaxf(a1.x * SC + b1.x, 0.f), fmaxf(a1.y * SC + b1.y, 0.f),
                          fmaxf(a1.z * SC + b1.z, 0.f), fmaxf(a1.w * SC + b1.w, 0.f));
  hv4[grp][lane * 2] = h0;
  hv4[grp][lane * 2 + 1] = h1;
  __syncthreads();

  if (lane < 54) {
    const float* w; float bb;
    if (lane < 18) { w = w_score + lane * 512; bb = b_score[lane]; }
    else           { w = w_delta + (lane - 18) * 512; bb = b_delta[lane - 18]; }
    const float4* w4 = (const float4*)w;
    float s = 0.f;
#pragma unroll 4
    for (int q = 0; q < 128; ++q) {
      float4 a = hv4[grp][q], b = w4[q];
      s += a.x * b.x + a.y * b.y + a.z * b.z + a.w * b.w;
    }
    outv[grp][lane] = s + bb;
  }
  __syncthreads();
  if (lane < 9) {
    int k = lane;
    float s0 = outv[grp][2 * k], s1 = outv[grp][2 * k + 1];
    float mx = fmaxf(s0, s1);
    float e0 = expf(s0 - mx), e1 = expf(s1 - mx);
    float f = e1 / (e0 + e1);
    double ratio = (k < 3) ? 0.5 : ((k < 6) ? 1.0 : 2.0);
    int si = k - (k / 3) * 3;
    double scale = (si == 0) ? 8.0 : ((si == 1) ? 16.0 : 32.0);
    double sq = sqrt(ratio);
    double wsd = 16.0 * scale / sq;
    double hsd = 16.0 * scale * sq;
    int y = p / 50, x = p - (p / 50) * 50;
    double cxd = ((double)x + 0.5) * 16.0;
    double cyd = ((double)y + 0.5) * 16.0;
    float ax1 = (float)(cxd - wsd / 2.0);
    float ay1 = (float)(cyd - hsd / 2.0);
    float ax2 = (float)(cxd + wsd / 2.0);
    float ay2 = (float)(cyd + hsd / 2.0);
    float aw = ax2 - ax1, ah = ay2 - ay1;
    float axc = ax1 + aw * 0.5f, ayc = ay1 + ah * 0.5f;
    float d0 = outv[grp][18 + 4 * k], d1 = outv[grp][18 + 4 * k + 1];
    float d2 = outv[grp][18 + 4 * k + 2], d3 = outv[grp][18 + 4 * k + 3];
    float cx = axc + d0 * aw, cy = ayc + d1 * ah;
    float bw = aw * expf(d2), bh = ah * expf(d3);
    float bx1 = fminf(fmaxf(cx - bw * 0.5f, 0.f), 800.f);
    float by1 = fminf(fmaxf(cy - bh * 0.5f, 0.f), 800.f);
    float bx2 = fminf(fmaxf(cx + bw * 0.5f, 0.f), 800.f);
    float by2 = fminf(fmaxf(cy + bh * 0.5f, 0.f), 800.f);
    int idx = p * 9 + k;
    boxes[idx] = make_float4(bx1, by1, bx2, by2);
    u64 key = ((u64)__float_as_uint(f) << 32) | (u64)(0xFFFFFFFFu - (unsigned)idx);
    keys[idx] = key;
    atomicAdd(&hist[(unsigned)(key >> 46)], 1);
  }
}

// ============ K4 scan ============
__global__ __launch_bounds__(1024) void k4_scan(const int* __restrict__ hist,
    int* __restrict__ cur, int* __restrict__ nbig, int* __restrict__ wl)
{
  __shared__ int ps[1024];
  int t = threadIdx.x;
  int local[64];
  int s = 0;
#pragma unroll
  for (int j = 0; j < 64; ++j) { local[j] = hist[t * 64 + j]; s += local[j]; }
  int mysum = s;
  ps[t] = s;
  __syncthreads();
  for (int d = 1; d < 1024; d <<= 1) {
    int v = ps[t];
    int u = (t >= d) ? ps[t - d] : 0;
    __syncthreads();
    ps[t] = v + u;
    __syncthreads();
  }
  int base = ps[t] - mysum;
#pragma unroll
  for (int j = 0; j < 64; ++j) {
    int b = t * 64 + j;
    cur[b] = base;
    if (local[j] > THRESH) { int w = atomicAdd(nbig, 1); wl[w] = b; }
    base += local[j];
  }
}

// ============ K4 scatter: wave-aggregated atomics ============
__global__ __launch_bounds__(256) void k4_scatter(const u64* __restrict__ keys,
    int* __restrict__ cur, u64* __restrict__ membuf)
{
  int i = blockIdx.x * 256 + threadIdx.x;
  int lane = threadIdx.x & 63;
  bool valid = i < NA;
  u64 k = valid ? keys[i] : 0ull;
  unsigned b = (unsigned)(k >> 46);
  int pos = 0;
  u64 mask = __ballot(valid);
  while (mask) {
    int lead = __builtin_ctzll(mask);
    unsigned lb = (unsigned)__shfl((int)b, lead);
    u64 same = __ballot(valid && b == lb) & mask;
    int cnt = __popcll(same);
    int base = 0;
    if (lane == lead) base = atomicAdd(&cur[lb], cnt);
    base = __shfl(base, lead);
    if (valid && ((same >> lane) & 1ull)) {
      int rank = __popcll(same & ((1ull << lane) - 1ull));
      pos = base + rank;
    }
    mask &= ~same;
  }
  if (valid) membuf[pos] = k;
}

// ============ K4 select ============
__global__ __launch_bounds__(1024) void k4_select(const u64* __restrict__ keys,
    const int* __restrict__ hist, const int* __restrict__ cur,
    const int* __restrict__ nbig, const int* __restrict__ wl,
    const u64* __restrict__ membuf, u64* __restrict__ membuf2,
    const float4* __restrict__ boxes, float4* __restrict__ cand,
    float* __restrict__ areas)
{
  __shared__ int cnt[NSUB];
  __shared__ int cur2[NSUB];
  __shared__ int ps[1024];
  int t = threadIdx.x;
  if (blockIdx.x < RANKBLKS) {
    int i = blockIdx.x * 1024 + t;
    if (i >= NA) return;
    u64 my = keys[i];
    unsigned b = (unsigned)(my >> 46);
    int cb = hist[b];
    if (cb > THRESH) return;
    int hi = cur[b];
    int lo = hi - cb;
    int r = NA - hi;
    for (int p = lo; p < hi; ++p) r += (membuf[p] > my) ? 1 : 0;
    if (r < TOPN) {
      unsigned idx = 0xFFFFFFFFu - (unsigned)my;
      float4 bx = boxes[idx];
      cand[r] = bx;
      areas[r] = (bx.z - bx.x) * (bx.w - bx.y);
    }
    return;
  }
  int nb = *nbig;
  for (int wi = blockIdx.x - RANKBLKS; wi < nb; wi += gridDim.x - RANKBLKS) {
    int b = wl[wi];
    int hi = cur[b], S = hist[b], lo = hi - S;
    for (int j = t; j < NSUB; j += 1024) cnt[j] = 0;
    __syncthreads();
    for (int e = lo + t; e < hi; e += 1024)
      atomicAdd(&cnt[(unsigned)(membuf[e] >> 33) & (NSUB - 1)], 1);
    __syncthreads();
    int loc[8], s = 0;
#pragma unroll
    for (int j = 0; j < 8; ++j) { loc[j] = cnt[t * 8 + j]; s += loc[j]; }
    ps[t] = s;
    __syncthreads();
    for (int d = 1; d < 1024; d <<= 1) {
      int v = ps[t];
      int u = (t >= d) ? ps[t - d] : 0;
      __syncthreads();
      ps[t] = v + u;
      __syncthreads();
    }
    int run = ps[1023] - ps[t];
#pragma unroll
    for (int j = 7; j >= 0; --j) {
      cur2[t * 8 + j] = lo + run;
      run += loc[j];
    }
    __syncthreads();
    for (int e = lo + t; e < hi; e += 1024) {
      u64 k = membuf[e];
      int p = atomicAdd(&cur2[(unsigned)(k >> 33) & (NSUB - 1)], 1);
      membuf2[p] = k;
    }
    __syncthreads();
    for (int e = lo + t; e < hi; e += 1024) {
      u64 my = membuf2[e];
      unsigned b2 = (unsigned)(my >> 33) & (NSUB - 1);
      int end = cur2[b2], start = end - cnt[b2];
      int r = (NA - hi) + (start - lo);
      for (int p = start; p < end; ++p) r += (membuf2[p] > my) ? 1 : 0;
      if (r < TOPN) {
        unsigned idx = 0xFFFFFFFFu - (unsigned)my;
        float4 bx = boxes[idx];
        cand[r] = bx;
        areas[r] = (bx.z - bx.x) * (bx.w - bx.y);
      }
    }
    __syncthreads();
  }
}

// ---------------- K5: IoU > 0.7 bit matrix ----------------
__global__ __launch_bounds__(256) void k5_iou(const float4* __restrict__ cand,
    const float* __restrict__ areas, u64* __restrict__ rowbuf)
{
  __shared__ float4 bj[64];
  __shared__ float aj[64];
  int jw = blockIdx.x;
  int i = blockIdx.y * 256 + threadIdx.x;
  if (threadIdx.x < 64) {
    int j = jw * 64 + threadIdx.x;
    bj[threadIdx.x] = (j < TOPN) ? cand[j] : make_float4(0.f, 0.f, 0.f, 0.f);
    aj[threadIdx.x] = (j < TOPN) ? areas[j] : 0.f;
  }
  __syncthreads();
  if (i >= TOPN) return;
  u64 word = 0ull;
  if (jw * 64 + 63 > i) {
    float4 bi = cand[i];
    float ai = areas[i];
#pragma unroll 8
    for (int b = 0; b < 64; ++b) {
      float4 bb = bj[b];
      float lx = fmaxf(bi.x, bb.x), ly = fmaxf(bi.y, bb.y);
      float rx = fminf(bi.z, bb.z), ry = fminf(bi.w, bb.w);
      float ww = fmaxf(rx - lx, 0.f), hh = fmaxf(ry - ly, 0.f);
      float inter = ww * hh;
      float iou = inter / (ai + aj[b] - inter + 1e-9f);
      int j = jw * 64 + b;
      if (iou > 0.7f && j > i && j < TOPN) word |= 1ull << b;
    }
  }
  rowbuf[(size_t)i * 96 + jw] = word;
}

// ---------------- K6: greedy NMS scan ----------------
__global__ __launch_bounds__(256) void k6_scan(const u64* __restrict__ rowbuf,
    const float4* __restrict__ cand, float4* __restrict__ rois)
{
  __shared__ u64 stage[64 * 97];
  __shared__ u64 sup[94];
  __shared__ int prefS[94];
  __shared__ int baseU_sh;
  int tid = threadIdx.x;
  if (tid < 94) sup[tid] = 0ull;
  if (tid == 0) baseU_sh = 0;

  u64 pre[24];
#pragma unroll
  for (int j = 0; j < 24; ++j) {
    int o = j * 256 + tid;
    int b = o / 94, w = o - b * 94;
    pre[j] = (o < 6016) ? rowbuf[(size_t)b * 96 + w] : 0ull;
  }
  __syncthreads();

  for (int c = 0; c < 94; ++c) {
#pragma unroll
    for (int j = 0; j < 24; ++j) {
      int o = j * 256 + tid;
      int b = o / 94, w = o - b * 94;
      if (o < 6016) stage[b * 97 + w] = pre[j];
    }
    __syncthreads();
    if (c + 1 < 94) {
#pragma unroll
      for (int j = 0; j < 24; ++j) {
        int o = j * 256 + tid;
        int b = o / 94, w = o - b * 94;
        pre[j] = (o < 6016) ? rowbuf[((size_t)(c + 1) * 64 + b) * 96 + w] : 0ull;
      }
    }
    u64 valid = (c == 93) ? ((1ull << 48) - 1ull) : ~0ull;
    u64 sup_c = sup[c];
    u64 live0 = ~sup_c & valid;
    u64 rw = stage[(tid & 63) * 97 + c];
    u64 live = live0, keep = 0ull;
    while (live) {
      int b = __builtin_ctzll(live);
      keep |= 1ull << b;
      u64 rb = (u64)__shfl((long long)rw, b);
      live &= ~rb;
      live &= ~(1ull << b);
    }
    int baseU = baseU_sh;
    if (tid < 64 && ((keep >> tid) & 1ull)) {
      u64 below = (tid == 0) ? 0ull : (keep & ((1ull << tid) - 1ull));
      int pos = baseU + __popcll(below);
      if (pos < NKEEP) rois[pos] = cand[c * 64 + tid];
    }
    __syncthreads();
    if (tid == 0) baseU_sh = baseU + __popcll(keep);
    if (tid == 64) sup[c] = sup_c | (live0 & ~keep);
    for (int w = c + 1 + tid; w < 94; w += 256) {
      u64 a = sup[w];
      u64 kk = keep;
      while (kk) {
        int b = __builtin_ctzll(kk);
        kk &= kk - 1;
        a |= stage[b * 97 + w];
      }
      sup[w] = a;
    }
    __syncthreads();
    if (baseU_sh >= NKEEP) break;
  }

  int totU = baseU_sh;
  if (totU < NKEEP) {
    if (tid == 0) {
      int s = 0;
      for (int w = 0; w < 94; ++w) { prefS[w] = s; s += __popcll(sup[w]); }
    }
    __syncthreads();
    for (int i = tid; i < TOPN; i += 256) {
      int w = i >> 6, b = i & 63;
      u64 sw = sup[w];
      if ((sw >> b) & 1ull) {
        u64 below = (b == 0) ? 0ull : (sw & ((1ull << b) - 1ull));
        int pos = totU + prefS[w] + __popcll(below);
        if (pos < NKEEP) rois[pos] = cand[i];
      }
    }
  }
}

// ---------------- K7: roi_align, coalesced-write layout ----------------
// grid = 3136 blocks (step,g), 320 threads (m = ROI). Thread m computes 8 elements
// k = step*64+g*8+e and writes ONE contiguous ushort8 -> fully coalesced across m.
__global__ __launch_bounds__(320) void k7_roi(const float4* __restrict__ rois,
    const float* __restrict__ feat_t, unsigned short* __restrict__ pool_bf)
{
  int step = blockIdx.x >> 3, g = blockIdx.x & 7;
  int m = threadIdx.x;
  bool rok = m < NKEEP;
  float4 box = rok ? rois[m] : make_float4(0.f, 0.f, 0.f, 0.f);
  float x1 = box.x * 0.0625f, y1 = box.y * 0.0625f;
  float x2 = box.z * 0.0625f, y2 = box.w * 0.0625f;
  float dxs = (x2 - x1) / 7.f, dys = (y2 - y1) / 7.f;
  int kbase = step * 64 + g * 8;

  ushort8 outv;
#pragma unroll
  for (int e = 0; e < 8; ++e) {
    int k = kbase + e;
    int c = k / 49;
    int s = k - c * 49;
    int py = s / 7, px = s - (s / 7) * 7;
    float acc = 0.f;
#pragma unroll
    for (int sy = 0; sy < 2; ++sy) {
#pragma unroll
      for (int sx = 0; sx < 2; ++sx) {
        float offx = ((float)(2 * px + sx) + 0.5f) * 0.5f;
        float offy = ((float)(2 * py + sy) + 0.5f) * 0.5f;
        float xs = x1 + offx * dxs;
        float ys = y1 + offy * dys;
        float x0f = floorf(xs), y0f = floorf(ys);
        float lx = xs - x0f, ly = ys - y0f;
        int x0i = (int)fminf(fmaxf(x0f, 0.f), 49.f);
        int x1i = (int)fminf(fmaxf(x0f + 1.f, 0.f), 49.f);
        int y0i = (int)fminf(fmaxf(y0f, 0.f), 49.f);
        int y1i = (int)fminf(fmaxf(y0f + 1.f, 0.f), 49.f);
        float f00 = feat_t[(size_t)(y0i * 50 + x0i) * 512 + c];
        float f01 = feat_t[(size_t)(y0i * 50 + x1i) * 512 + c];
        float f10 = feat_t[(size_t)(y1i * 50 + x0i) * 512 + c];
        float f11 = feat_t[(size_t)(y1i * 50 + x1i) * 512 + c];
        acc += (1.f - ly) * (1.f - lx) * f00 + (1.f - ly) * lx * f01
             + ly * (1.f - lx) * f10 + ly * lx * f11;
      }
    }
    outv[e] = rok ? f2bf(acc * 0.25f) : (unsigned short)0;
  }
  *(ushort8*)&pool_bf[(size_t)step * 20480 + (g * 320 + m) * 8] = outv;
}

// ---------------- K8: fc7 GEMM bf16 MFMA, streaming W ----------------
__global__ __launch_bounds__(512) void k8_gemm(const unsigned short* __restrict__ Ap,
    const float* __restrict__ W, float* __restrict__ partial, int spk)
{
  __shared__ __align__(16) unsigned short As[8 * 320 * 8];
  __shared__ __align__(16) unsigned short Bs[8 * 128 * 8];
  int tid = threadIdx.x;
  int lane = tid & 63, wv = tid >> 6;
  int wm = wv & 1, wn = wv >> 1;
  int n0 = blockIdx.x * 128;
  int by = blockIdx.y;
  int steps = min(spk, KSTEPS - by * spk);

  f32x4 acc[10][2];
#pragma unroll
  for (int i = 0; i < 10; ++i)
#pragma unroll
    for (int j = 0; j < 2; ++j) acc[i][j] = (f32x4){0.f, 0.f, 0.f, 0.f};

  ushort8 aReg[5];
  float4 wReg[4];

  auto LOAD = [&](int t) {
    size_t abase = (size_t)(by * spk + t) * 20480;
    int k0 = (by * spk + t) * 64;
#pragma unroll
    for (int j = 0; j < 5; ++j)
      aReg[j] = *(const ushort8*)(Ap + abase + (size_t)(j * 512 + tid) * 8);
#pragma unroll
    for (int j = 0; j < 4; ++j) {
      int fq = j * 512 + tid;
      int n = fq >> 4, kq = fq & 15;
      wReg[j] = *(const float4*)(W + (size_t)(n0 + n) * 25088 + k0 + kq * 4);
    }
  };

  LOAD(0);
  for (int t = 0; t < steps; ++t) {
    u64 pk[4];
#pragma unroll
    for (int j = 0; j < 4; ++j) {
      float4 v = wReg[j];
      pk[j] = (u64)f2bf(v.x) | ((u64)f2bf(v.y) << 16)
            | ((u64)f2bf(v.z) << 32) | ((u64)f2bf(v.w) << 48);
    }
    __syncthreads();
#pragma unroll
    for (int j = 0; j < 5; ++j)
      ((ushort8*)As)[j * 512 + tid] = aReg[j];
#pragma unroll
    for (int j = 0; j < 4; ++j) {
      int fq = j * 512 + tid;
      int n = fq >> 4, kq = fq & 15;
      *(u64*)&Bs[((kq >> 1) * 128 + n) * 8 + (kq & 1) * 4] = pk[j];
    }
    __syncthreads();
    if (t + 1 < steps) LOAD(t + 1);
#pragma unroll
    for (int kk = 0; kk < 2; ++kk) {
      int g = kk * 4 + (lane >> 4);
      short8 b0 = ((const short8*)Bs)[g * 128 + wn * 32 + (lane & 15)];
      short8 b1 = ((const short8*)Bs)[g * 128 + wn * 32 + 16 + (lane & 15)];
#pragma unroll
      for (int fm = 0; fm < 10; ++fm) {
        short8 a = ((const short8*)As)[g * 320 + wm * 160 + fm * 16 + (lane & 15)];
        acc[fm][0] = __builtin_amdgcn_mfma_f32_16x16x32_bf16(a, b0, acc[fm][0], 0, 0, 0);
        acc[fm][1] = __builtin_amdgcn_mfma_f32_16x16x32_bf16(a, b1, acc[fm][1], 0, 0, 0);
      }
    }
  }
  float* P = partial + (size_t)(by * 32 + blockIdx.x) * (320 * 128);
#pragma unroll
  for (int fm = 0; fm < 10; ++fm)
#pragma unroll
    for (int fn = 0; fn < 2; ++fn)
#pragma unroll
      for (int r = 0; r < 4; ++r) {
        int m = wm * 160 + fm * 16 + (lane >> 4) * 4 + r;
        int n = wn * 32 + fn * 16 + (lane & 15);
        P[m * 128 + n] = acc[fm][fn][r];
      }
}

// ---------------- K9a: reduce k8 partials -> fc7 f32 (+bias/ReLU) ----------------
__global__ __launch_bounds__(256) void k9a_reduce(const float* __restrict__ partial,
    const float* __restrict__ bias, float* __restrict__ fc7, int KS)
{
  int idx = blockIdx.x * 256 + threadIdx.x;
  if (idx >= 300 * 4096) return;
  int m = idx >> 12, n = idx & 4095;
  int nt = n >> 7, nn = n & 127;
  float s = 0.f;
  for (int ks = 0; ks < KS; ++ks)
    s += partial[((size_t)(ks * 32 + nt) * 320 + m) * 128 + nn];
  s += bias[n];
  fc7[idx] = fmaxf(s, 0.f);
}

// ---------------- K9b: cls/reg heads, one wave per (m, o) dot product ----------------
__global__ __launch_bounds__(256) void k9b_heads(const float* __restrict__ fc7,
    const float* __restrict__ wc, const float* __restrict__ bc,
    const float* __restrict__ wr, const float* __restrict__ br,
    float* __restrict__ out)
{
  int wid = blockIdx.x * 4 + (threadIdx.x >> 6);
  int lane = threadIdx.x & 63;
  if (wid >= 300 * 105) return;
  int m = wid / 105, o = wid - m * 105;
  const float* w; float b;
  if (o < 21) { w = wc + (size_t)o * 4096; b = bc[o]; }
  else        { w = wr + (size_t)(o - 21) * 4096; b = br[o - 21]; }
  const float4* f4 = (const float4*)(fc7 + (size_t)m * 4096);
  const float4* w4 = (const float4*)w;
  float s = 0.f;
#pragma unroll
  for (int i = 0; i < 16; ++i) {
    float4 a = f4[i * 64 + lane];
    float4 ww = w4[i * 64 + lane];
    s += a.x * ww.x + a.y * ww.y + a.z * ww.z + a.w * ww.w;
  }
#pragma unroll
  for (int d = 32; d > 0; d >>= 1) s += __shfl_down(s, d);
  if (lane == 0) {
    s += b;
    if (o < 21) out[m * 21 + o] = s;
    else        out[6300 + m * 84 + (o - 21)] = s;
  }
}

extern "C" void kernel_launch(void* const* d_in, const int* in_sizes, int n_in,
                              void* d_out, int out_size, void* d_ws, size_t ws_size,
                              hipStream_t stream)
{
  (void)in_sizes; (void)n_in; (void)out_size;
  const float* img    = (const float*)d_in[0];
  const float* w_feat = (const float*)d_in[1];
  const float* b_feat = (const float*)d_in[2];
  const float* w_rpn  = (const float*)d_in[3];
  const float* b_rpn  = (const float*)d_in[4];
  const float* w_score= (const float*)d_in[5];
  const float* b_score= (const float*)d_in[6];
  const float* w_delta= (const float*)d_in[7];
  const float* b_delta= (const float*)d_in[8];
  const float* w_fc7  = (const float*)d_in[9];
  const float* b_fc7  = (const float*)d_in[10];
  const float* w_cls  = (const float*)d_in[11];
  const float* b_cls  = (const float*)d_in[12];
  const float* w_reg  = (const float*)d_in[13];
  const float* b_reg  = (const float*)d_in[14];
  float* out = (float*)d_out;

  char* ws = (char*)d_ws;
  size_t off = 0;
  auto alloc = [&](size_t bytes) -> void* {
    void* p = ws + off;
    off = (off + bytes + 511) & ~(size_t)511;
    return p;
  };
  float* feat_t  = (float*)alloc(5120000);
  unsigned short* Fhi = (unsigned short*)alloc((size_t)NPOS * 512 * 2);
  unsigned short* Flo = (unsigned short*)alloc((size_t)NPOS * 512 * 2);
  unsigned short* Whi = (unsigned short*)alloc((size_t)512 * 4608 * 2);
  unsigned short* Wlo = (unsigned short*)alloc((size_t)512 * 4608 * 2);
  float4* boxes  = (float4*)alloc((size_t)NA * 16);
  u64* keys      = (u64*)alloc((size_t)NA * 8);
  int* histbuf   = (int*)alloc((size_t)(NBUCK + 1 + 256) * 4);
  int* hist = histbuf; int* nbig = histbuf + NBUCK; int* wl = histbuf + NBUCK + 1;
  int* bcur      = (int*)alloc((size_t)NBUCK * 4);
  u64* membuf    = (u64*)alloc((size_t)NA * 8);
  u64* membuf2   = (u64*)alloc((size_t)NA * 8);
  float4* cand   = (float4*)alloc((size_t)TOPN * 16);
  float* areas   = (float*)alloc((size_t)TOPN * 4);
  u64* rowbuf    = (u64*)alloc((size_t)TOPN * 96 * 8);
  float4* rois   = (float4*)alloc(NKEEP * 16);
  unsigned short* pool_bf = (unsigned short*)alloc((size_t)KSTEPS * 20480 * 2);
  float* fc7     = (float*)alloc((size_t)300 * 4096 * 4);

  size_t avail = (ws_size > off) ? (ws_size - off) : 0;
  float* P_sh = (float*)(ws + off);
  int KS1 = 8, KS8 = 8;
  while (KS1 > 1 && (size_t)KS1 * 80 * 16384 * 4 > avail) KS1 >>= 1;
  while (KS8 > 1 && (size_t)KS8 * 32 * 320 * 128 * 4 > avail) KS8 >>= 1;
  int klen1 = 768 / KS1;
  int spk8 = (KSTEPS + KS8 - 1) / KS8;

  kw_prep<<<512, 256, 0, stream>>>(w_rpn, Whi, Wlo, histbuf);
  k1_gemm<<<dim3(20, 4, KS1), 256, 0, stream>>>(img, w_feat, P_sh, klen1);
  kred1<<<(NPOS * 512 + 255) / 256, 256, 0, stream>>>(P_sh, b_feat, feat_t, Fhi, Flo, KS1);
  k2_mfma<<<dim3(4, 16, 8), 256, 0, stream>>>(Fhi, Flo, Whi, Wlo, P_sh);
  k3_fused<<<625, 256, 0, stream>>>(P_sh, b_rpn, w_score, b_score, w_delta, b_delta,
                                    boxes, keys, hist);
  k4_scan   <<<1, 1024, 0, stream>>>(hist, bcur, nbig, wl);
  k4_scatter<<<88, 256, 0, stream>>>(keys, bcur, membuf);
  k4_select <<<RANKBLKS + 64, 1024, 0, stream>>>(keys, hist, bcur, nbig, wl,
                                                 membuf, membuf2, boxes, cand, areas);
  k5_iou    <<<dim3(94, 24), 256, 0, stream>>>(cand, areas, rowbuf);
  k6_scan   <<<1, 256, 0, stream>>>(rowbuf, cand, rois);
  k7_roi    <<<3136, 320, 0, stream>>>(rois, feat_t, pool_bf);
  k8_gemm   <<<dim3(32, KS8), 512, 0, stream>>>(pool_bf, w_fc7, P_sh, spk8);
  k9a_reduce<<<(300 * 4096 + 255) / 256, 256, 0, stream>>>(P_sh, b_fc7, fc7, KS8);
  k9b_heads<<<(300 * 105 + 3) / 4, 256, 0, stream>>>(fc7, w_cls, b_cls, w_reg, b_reg, out);
}

// Round 20
// 605.618 us; speedup vs baseline: 5.0783x; 1.3937x over previous
//
#include <hip/hip_runtime.h>
#include <cstdint>

typedef short  short8  __attribute__((ext_vector_type(8)));
typedef unsigned short ushort8 __attribute__((ext_vector_type(8)));
typedef _Float16 half8 __attribute__((ext_vector_type(8)));
typedef float  f32x4   __attribute__((ext_vector_type(4)));
typedef unsigned long long u64;

#define NPOS 2500
#define NA   22500
#define TOPN 6000
#define NKEEP 300
#define NBUCK 65536
#define THRESH 512
#define NSUB 8192
#define KSTEPS 392   // 25088 / 64
#define RANKBLKS 22  // ceil(22500/1024)

__device__ __forceinline__ unsigned short f2bf(float f) {
  unsigned u = __float_as_uint(f);
  return (unsigned short)((u + 0x7FFFu + ((u >> 16) & 1u)) >> 16);
}

// ============ KW: w_rpn transpose/split via LDS (coalesced both sides) + hist zero ============
__global__ __launch_bounds__(256) void kw_prep(const float* __restrict__ wr,
    unsigned short* __restrict__ Whi, unsigned short* __restrict__ Wlo,
    int* __restrict__ histbuf)
{
  __shared__ float wrow[4608];
  int n = blockIdx.x, tid = threadIdx.x;
  {
    int gtid = n * 256 + tid;
    if (gtid < NBUCK + 1 + 256) histbuf[gtid] = 0;
  }
  for (int i = tid; i < 4608; i += 256) wrow[i] = wr[(size_t)n * 4608 + i];
  __syncthreads();
  for (int o = tid; o < 4608; o += 256) {
    int s = o >> 9, c = o & 511;
    float w = wrow[c * 9 + s] * 1024.f;
    _Float16 hi = (_Float16)w;
    _Float16 lo = (_Float16)(w - (float)hi);
    ((_Float16*)Whi)[(size_t)n * 4608 + o] = hi;
    ((_Float16*)Wlo)[(size_t)n * 4608 + o] = lo;
  }
}

// ============ K1: patchify conv f32 GEMM (pure) ============
__global__ __launch_bounds__(256) void k1_gemm(const float* __restrict__ Asrc,
    const float* __restrict__ Bsrc, float* __restrict__ P, int klen)
{
  __shared__ float As[32][128];
  __shared__ float Bs[32][132];
  int tid = threadIdx.x;
  int tx = tid & 15, ty = tid >> 4;
  int mt = blockIdx.x, nt = blockIdx.y;
  int m0 = mt * 128, n0 = nt * 128;
  int kbase = blockIdx.z * klen;

  int m_loc = tid & 127;
  int half = tid >> 7;
  int gm = m0 + m_loc;
  int y = gm / 50, x = gm - y * 50;
  bool mok = gm < NPOS;

  float acc[8][8] = {};

  for (int kt = 0; kt < klen; kt += 32) {
    int kb = kbase + kt;
    int k0 = kb + half * 16;
    int ci = k0 >> 8, r = (k0 >> 4) & 15;
    const float* src = Asrc + ci * 640000 + (y * 16 + r) * 800 + x * 16;
#pragma unroll
    for (int j = 0; j < 4; ++j) {
      float4 v = mok ? *(const float4*)(src + j * 4) : make_float4(0.f, 0.f, 0.f, 0.f);
      As[half * 16 + j * 4 + 0][m_loc] = v.x;
      As[half * 16 + j * 4 + 1][m_loc] = v.y;
      As[half * 16 + j * 4 + 2][m_loc] = v.z;
      As[half * 16 + j * 4 + 3][m_loc] = v.w;
    }
#pragma unroll
    for (int i = 0; i < 4; ++i) {
      int e = i * 256 + tid;
      int k4 = e & 7, n = e >> 3;
      float4 v = *(const float4*)(Bsrc + (size_t)(n0 + n) * 768 + kb + k4 * 4);
      Bs[k4 * 4 + 0][n] = v.x;
      Bs[k4 * 4 + 1][n] = v.y;
      Bs[k4 * 4 + 2][n] = v.z;
      Bs[k4 * 4 + 3][n] = v.w;
    }
    __syncthreads();
#pragma unroll 8
    for (int k = 0; k < 32; ++k) {
      float4 a0 = *(const float4*)&As[k][ty * 8];
      float4 a1 = *(const float4*)&As[k][ty * 8 + 4];
      float4 b0 = *(const float4*)&Bs[k][tx * 8];
      float4 b1 = *(const float4*)&Bs[k][tx * 8 + 4];
      float av[8] = {a0.x, a0.y, a0.z, a0.w, a1.x, a1.y, a1.z, a1.w};
      float bv[8] = {b0.x, b0.y, b0.z, b0.w, b1.x, b1.y, b1.z, b1.w};
#pragma unroll
      for (int i2 = 0; i2 < 8; ++i2)
#pragma unroll
        for (int j2 = 0; j2 < 8; ++j2) acc[i2][j2] += av[i2] * bv[j2];
    }
    __syncthreads();
  }
  float* Pp = P + ((size_t)(blockIdx.z * 20 + mt) * 4 + nt) * 16384;
#pragma unroll
  for (int i = 0; i < 8; ++i) {
    float4 v0 = {acc[i][0], acc[i][1], acc[i][2], acc[i][3]};
    float4 v1 = {acc[i][4], acc[i][5], acc[i][6], acc[i][7]};
    *(float4*)&Pp[(ty * 8 + i) * 128 + tx * 8] = v0;
    *(float4*)&Pp[(ty * 8 + i) * 128 + tx * 8 + 4] = v1;
  }
}

// kred1: reduce k1 partials -> feat_t f32 + feat hi/lo f16 (x2048)
__global__ __launch_bounds__(256) void kred1(const float* __restrict__ P,
    const float* __restrict__ bias, float* __restrict__ feat_t,
    unsigned short* __restrict__ Fhi, unsigned short* __restrict__ Flo, int KS)
{
  int idx = blockIdx.x * 256 + threadIdx.x;
  if (idx >= NPOS * 512) return;
  int m = idx >> 9, n = idx & 511;
  int mt = m >> 7, ml = m & 127, nt = n >> 7, nl = n & 127;
  float s = 0.f;
  for (int z = 0; z < KS; ++z)
    s += P[(((size_t)(z * 20 + mt) * 4 + nt) << 14) + ml * 128 + nl];
  s += bias[n];
  feat_t[idx] = s;
  float fs = s * 2048.f;
  _Float16 hi = (_Float16)fs;
  _Float16 lo = (_Float16)(fs - (float)hi);
  ((_Float16*)Fhi)[idx] = hi;
  ((_Float16*)Flo)[idx] = lo;
}

// ============ K2: RPN split-f16 MFMA GEMM ============
__global__ __launch_bounds__(256) void k2_mfma(
    const unsigned short* __restrict__ Fhi, const unsigned short* __restrict__ Flo,
    const unsigned short* __restrict__ Whi, const unsigned short* __restrict__ Wlo,
    float* __restrict__ partial)
{
  __shared__ __align__(16) unsigned short As[8 * 162 * 8];
  __shared__ __align__(16) unsigned short Bs[8 * 130 * 8];
  int tid = threadIdx.x;
  int lane = tid & 63, wn = tid >> 6;
  int nt = blockIdx.x, mt = blockIdx.y, z = blockIdx.z;
  int n0 = nt * 128;

  f32x4 acc[10][2];
#pragma unroll
  for (int i = 0; i < 10; ++i)
#pragma unroll
    for (int j = 0; j < 2; ++j) acc[i][j] = (f32x4){0.f, 0.f, 0.f, 0.f};

  int yv[5], xv[5], slotA[5], gof[5];
  bool okv[5];
#pragma unroll
  for (int j = 0; j < 5; ++j) {
    int o = j * 256 + tid;
    int m = o >> 3, g = o & 7;
    int gm = mt * 160 + m;
    okv[j] = gm < NPOS;
    yv[j] = gm / 50;
    xv[j] = gm - yv[j] * 50;
    slotA[j] = g * 162 + m;
    gof[j] = g * 8;
  }

  ushort8 aR[5], bR[4];

  auto LOAD = [&](int t) {
    int tg = z * 27 + t;
    const unsigned short* Asrc = (tg < 144) ? Fhi : Flo;
    const unsigned short* Bsrc = (tg < 72 || tg >= 144) ? Whi : Wlo;
    int ks = (tg >= 144) ? (tg - 144) : ((tg >= 72) ? (tg - 72) : tg);
    int ki = ks * 64;
    int srow = ki >> 9;
    int c0 = ki & 511;
    int dy = srow / 3, dx = srow - (srow / 3) * 3;
#pragma unroll
    for (int j = 0; j < 5; ++j) {
      int yy = yv[j] + dy - 1, xx = xv[j] + dx - 1;
      ushort8 v = {0, 0, 0, 0, 0, 0, 0, 0};
      if (okv[j] && (unsigned)yy < 50u && (unsigned)xx < 50u)
        v = *(const ushort8*)(Asrc + (size_t)(yy * 50 + xx) * 512 + c0 + gof[j]);
      aR[j] = v;
    }
#pragma unroll
    for (int j = 0; j < 4; ++j) {
      int o = j * 256 + tid;
      int n = o >> 3, g = o & 7;
      bR[j] = *(const ushort8*)(Bsrc + (size_t)(n0 + n) * 4608 + ki + g * 8);
    }
  };

  LOAD(0);
  for (int t = 0; t < 27; ++t) {
    __syncthreads();
#pragma unroll
    for (int j = 0; j < 5; ++j)
      ((ushort8*)As)[slotA[j]] = aR[j];
#pragma unroll
    for (int j = 0; j < 4; ++j) {
      int o = j * 256 + tid;
      ((ushort8*)Bs)[(o & 7) * 130 + (o >> 3)] = bR[j];
    }
    __syncthreads();
    if (t + 1 < 27) LOAD(t + 1);
#pragma unroll
    for (int kk = 0; kk < 2; ++kk) {
      int g = kk * 4 + (lane >> 4);
      half8 b0 = ((const half8*)Bs)[g * 130 + wn * 32 + (lane & 15)];
      half8 b1 = ((const half8*)Bs)[g * 130 + wn * 32 + 16 + (lane & 15)];
#pragma unroll
      for (int fm = 0; fm < 10; ++fm) {
        half8 a = ((const half8*)As)[g * 162 + fm * 16 + (lane & 15)];
        acc[fm][0] = __builtin_amdgcn_mfma_f32_16x16x32_f16(a, b0, acc[fm][0], 0, 0, 0);
        acc[fm][1] = __builtin_amdgcn_mfma_f32_16x16x32_f16(a, b1, acc[fm][1], 0, 0, 0);
      }
    }
  }
  float* P = partial + ((size_t)(z * 16 + mt) * 4 + nt) * 20480;
#pragma unroll
  for (int fm = 0; fm < 10; ++fm)
#pragma unroll
    for (int fn = 0; fn < 2; ++fn)
#pragma unroll
      for (int r = 0; r < 4; ++r) {
        int m = fm * 16 + (lane >> 4) * 4 + r;
        int n = wn * 32 + fn * 16 + (lane & 15);
        P[m * 128 + n] = acc[fm][fn][r];
      }
}

// ---------------- K3 (fused): reduce k2 partials (/2^21) + bias/ReLU + heads + keys + hist ----------------
__global__ __launch_bounds__(256) void k3_fused(const float* __restrict__ P,
    const float* __restrict__ b_rpn,
    const float* __restrict__ w_score, const float* __restrict__ b_score,
    const float* __restrict__ w_delta, const float* __restrict__ b_delta,
    float4* __restrict__ boxes, u64* __restrict__ keys, int* __restrict__ hist)
{
  __shared__ float4 hv4[4][128];
  __shared__ float outv[4][54];
  int grp = threadIdx.x >> 6, lane = threadIdx.x & 63;
  int p = blockIdx.x * 4 + grp;
  int mt = p / 160, ml = p - mt * 160;
  int nt = lane >> 4;
  int nl8 = (lane * 8) & 127;

  float4 a0 = make_float4(0.f, 0.f, 0.f, 0.f);
  float4 a1 = make_float4(0.f, 0.f, 0.f, 0.f);
  for (int z = 0; z < 8; ++z) {
    const float* Pb = P + ((size_t)(z * 16 + mt) * 4 + nt) * 20480 + ml * 128 + nl8;
    float4 v0 = *(const float4*)Pb;
    float4 v1 = *(const float4*)(Pb + 4);
    a0.x += v0.x; a0.y += v0.y; a0.z += v0.z; a0.w += v0.w;
    a1.x += v1.x; a1.y += v1.y; a1.z += v1.z; a1.w += v1.w;
  }
  const float SC = 1.f / 2097152.f;
  const float4 b0 = *(const float4*)(b_rpn + lane * 8);
  const float4 b1 = *(const float4*)(b_rpn + lane * 8 + 4);
  float4 h0 = make_float4(fmaxf(a0.x * SC + b0.x, 0.f), fmaxf(a0.y * SC + b0.y, 0.f),
                          fmaxf(a0.z * SC + b0.z, 0.f), fmaxf(a0.w * SC + b0.w, 0.f));
  float4 h1 = make_float4(fmaxf(a1.x * SC + b1.x, 0.f), fmaxf(a1.y * SC + b1.y, 0.f),
                          fmaxf(a1.z * SC + b1.z, 0.f), fmaxf(a1.w * SC + b1.w, 0.f));
  hv4[grp][lane * 2] = h0;
  hv4[grp][lane * 2 + 1] = h1;
  __syncthreads();

  if (lane < 54) {
    const float* w; float bb;
    if (lane < 18) { w = w_score + lane * 512; bb = b_score[lane]; }
    else           { w = w_delta + (lane - 18) * 512; bb = b_delta[lane - 18]; }
    const float4* w4 = (const float4*)w;
    float s = 0.f;
#pragma unroll 4
    for (int q = 0; q < 128; ++q) {
      float4 a = hv4[grp][q], b = w4[q];
      s += a.x * b.x + a.y * b.y + a.z * b.z + a.w * b.w;
    }
    outv[grp][lane] = s + bb;
  }
  __syncthreads();
  if (lane < 9) {
    int k = lane;
    float s0 = outv[grp][2 * k], s1 = outv[grp][2 * k + 1];
    float mx = fmaxf(s0, s1);
    float e0 = expf(s0 - mx), e1 = expf(s1 - mx);
    float f = e1 / (e0 + e1);
    double ratio = (k < 3) ? 0.5 : ((k < 6) ? 1.0 : 2.0);
    int si = k - (k / 3) * 3;
    double scale = (si == 0) ? 8.0 : ((si == 1) ? 16.0 : 32.0);
    double sq = sqrt(ratio);
    double wsd = 16.0 * scale / sq;
    double hsd = 16.0 * scale * sq;
    int y = p / 50, x = p - (p / 50) * 50;
    double cxd = ((double)x + 0.5) * 16.0;
    double cyd = ((double)y + 0.5) * 16.0;
    float ax1 = (float)(cxd - wsd / 2.0);
    float ay1 = (float)(cyd - hsd / 2.0);
    float ax2 = (float)(cxd + wsd / 2.0);
    float ay2 = (float)(cyd + hsd / 2.0);
    float aw = ax2 - ax1, ah = ay2 - ay1;
    float axc = ax1 + aw * 0.5f, ayc = ay1 + ah * 0.5f;
    float d0 = outv[grp][18 + 4 * k], d1 = outv[grp][18 + 4 * k + 1];
    float d2 = outv[grp][18 + 4 * k + 2], d3 = outv[grp][18 + 4 * k + 3];
    float cx = axc + d0 * aw, cy = ayc + d1 * ah;
    float bw = aw * expf(d2), bh = ah * expf(d3);
    float bx1 = fminf(fmaxf(cx - bw * 0.5f, 0.f), 800.f);
    float by1 = fminf(fmaxf(cy - bh * 0.5f, 0.f), 800.f);
    float bx2 = fminf(fmaxf(cx + bw * 0.5f, 0.f), 800.f);
    float by2 = fminf(fmaxf(cy + bh * 0.5f, 0.f), 800.f);
    int idx = p * 9 + k;
    boxes[idx] = make_float4(bx1, by1, bx2, by2);
    u64 key = ((u64)__float_as_uint(f) << 32) | (u64)(0xFFFFFFFFu - (unsigned)idx);
    keys[idx] = key;
    atomicAdd(&hist[(unsigned)(key >> 46)], 1);
  }
}

// ============ K4 scan ============
__global__ __launch_bounds__(1024) void k4_scan(const int* __restrict__ hist,
    int* __restrict__ cur, int* __restrict__ nbig, int* __restrict__ wl)
{
  __shared__ int ps[1024];
  int t = threadIdx.x;
  int local[64];
  int s = 0;
#pragma unroll
  for (int j = 0; j < 64; ++j) { local[j] = hist[t * 64 + j]; s += local[j]; }
  int mysum = s;
  ps[t] = s;
  __syncthreads();
  for (int d = 1; d < 1024; d <<= 1) {
    int v = ps[t];
    int u = (t >= d) ? ps[t - d] : 0;
    __syncthreads();
    ps[t] = v + u;
    __syncthreads();
  }
  int base = ps[t] - mysum;
#pragma unroll
  for (int j = 0; j < 64; ++j) {
    int b = t * 64 + j;
    cur[b] = base;
    if (local[j] > THRESH) { int w = atomicAdd(nbig, 1); wl[w] = b; }
    base += local[j];
  }
}

// ============ K4 scatter: wave-aggregated atomics ============
__global__ __launch_bounds__(256) void k4_scatter(const u64* __restrict__ keys,
    int* __restrict__ cur, u64* __restrict__ membuf)
{
  int i = blockIdx.x * 256 + threadIdx.x;
  int lane = threadIdx.x & 63;
  bool valid = i < NA;
  u64 k = valid ? keys[i] : 0ull;
  unsigned b = (unsigned)(k >> 46);
  int pos = 0;
  u64 mask = __ballot(valid);
  while (mask) {
    int lead = __builtin_ctzll(mask);
    unsigned lb = (unsigned)__shfl((int)b, lead);
    u64 same = __ballot(valid && b == lb) & mask;
    int cnt = __popcll(same);
    int base = 0;
    if (lane == lead) base = atomicAdd(&cur[lb], cnt);
    base = __shfl(base, lead);
    if (valid && ((same >> lane) & 1ull)) {
      int rank = __popcll(same & ((1ull << lane) - 1ull));
      pos = base + rank;
    }
    mask &= ~same;
  }
  if (valid) membuf[pos] = k;
}

// ============ K4 select ============
__global__ __launch_bounds__(1024) void k4_select(const u64* __restrict__ keys,
    const int* __restrict__ hist, const int* __restrict__ cur,
    const int* __restrict__ nbig, const int* __restrict__ wl,
    const u64* __restrict__ membuf, u64* __restrict__ membuf2,
    const float4* __restrict__ boxes, float4* __restrict__ cand,
    float* __restrict__ areas)
{
  __shared__ int cnt[NSUB];
  __shared__ int cur2[NSUB];
  __shared__ int ps[1024];
  int t = threadIdx.x;
  if (blockIdx.x < RANKBLKS) {
    int i = blockIdx.x * 1024 + t;
    if (i >= NA) return;
    u64 my = keys[i];
    unsigned b = (unsigned)(my >> 46);
    int cb = hist[b];
    if (cb > THRESH) return;
    int hi = cur[b];
    int lo = hi - cb;
    int r = NA - hi;
    for (int p = lo; p < hi; ++p) r += (membuf[p] > my) ? 1 : 0;
    if (r < TOPN) {
      unsigned idx = 0xFFFFFFFFu - (unsigned)my;
      float4 bx = boxes[idx];
      cand[r] = bx;
      areas[r] = (bx.z - bx.x) * (bx.w - bx.y);
    }
    return;
  }
  int nb = *nbig;
  for (int wi = blockIdx.x - RANKBLKS; wi < nb; wi += gridDim.x - RANKBLKS) {
    int b = wl[wi];
    int hi = cur[b], S = hist[b], lo = hi - S;
    for (int j = t; j < NSUB; j += 1024) cnt[j] = 0;
    __syncthreads();
    for (int e = lo + t; e < hi; e += 1024)
      atomicAdd(&cnt[(unsigned)(membuf[e] >> 33) & (NSUB - 1)], 1);
    __syncthreads();
    int loc[8], s = 0;
#pragma unroll
    for (int j = 0; j < 8; ++j) { loc[j] = cnt[t * 8 + j]; s += loc[j]; }
    ps[t] = s;
    __syncthreads();
    for (int d = 1; d < 1024; d <<= 1) {
      int v = ps[t];
      int u = (t >= d) ? ps[t - d] : 0;
      __syncthreads();
      ps[t] = v + u;
      __syncthreads();
    }
    int run = ps[1023] - ps[t];
#pragma unroll
    for (int j = 7; j >= 0; --j) {
      cur2[t * 8 + j] = lo + run;
      run += loc[j];
    }
    __syncthreads();
    for (int e = lo + t; e < hi; e += 1024) {
      u64 k = membuf[e];
      int p = atomicAdd(&cur2[(unsigned)(k >> 33) & (NSUB - 1)], 1);
      membuf2[p] = k;
    }
    __syncthreads();
    for (int e = lo + t; e < hi; e += 1024) {
      u64 my = membuf2[e];
      unsigned b2 = (unsigned)(my >> 33) & (NSUB - 1);
      int end = cur2[b2], start = end - cnt[b2];
      int r = (NA - hi) + (start - lo);
      for (int p = start; p < end; ++p) r += (membuf2[p] > my) ? 1 : 0;
      if (r < TOPN) {
        unsigned idx = 0xFFFFFFFFu - (unsigned)my;
        float4 bx = boxes[idx];
        cand[r] = bx;
        areas[r] = (bx.z - bx.x) * (bx.w - bx.y);
      }
    }
    __syncthreads();
  }
}

// ---------------- K5: IoU > 0.7 bit matrix ----------------
__global__ __launch_bounds__(256) void k5_iou(const float4* __restrict__ cand,
    const float* __restrict__ areas, u64* __restrict__ rowbuf)
{
  __shared__ float4 bj[64];
  __shared__ float aj[64];
  int jw = blockIdx.x;
  int i = blockIdx.y * 256 + threadIdx.x;
  if (threadIdx.x < 64) {
    int j = jw * 64 + threadIdx.x;
    bj[threadIdx.x] = (j < TOPN) ? cand[j] : make_float4(0.f, 0.f, 0.f, 0.f);
    aj[threadIdx.x] = (j < TOPN) ? areas[j] : 0.f;
  }
  __syncthreads();
  if (i >= TOPN) return;
  u64 word = 0ull;
  if (jw * 64 + 63 > i) {
    float4 bi = cand[i];
    float ai = areas[i];
#pragma unroll 8
    for (int b = 0; b < 64; ++b) {
      float4 bb = bj[b];
      float lx = fmaxf(bi.x, bb.x), ly = fmaxf(bi.y, bb.y);
      float rx = fminf(bi.z, bb.z), ry = fminf(bi.w, bb.w);
      float ww = fmaxf(rx - lx, 0.f), hh = fmaxf(ry - ly, 0.f);
      float inter = ww * hh;
      float iou = inter / (ai + aj[b] - inter + 1e-9f);
      int j = jw * 64 + b;
      if (iou > 0.7f && j > i && j < TOPN) word |= 1ull << b;
    }
  }
  rowbuf[(size_t)i * 96 + jw] = word;
}

// ---------------- K6: greedy NMS scan ----------------
__global__ __launch_bounds__(256) void k6_scan(const u64* __restrict__ rowbuf,
    const float4* __restrict__ cand, float4* __restrict__ rois)
{
  __shared__ u64 stage[64 * 97];
  __shared__ u64 sup[94];
  __shared__ int prefS[94];
  __shared__ int baseU_sh;
  int tid = threadIdx.x;
  if (tid < 94) sup[tid] = 0ull;
  if (tid == 0) baseU_sh = 0;

  u64 pre[24];
#pragma unroll
  for (int j = 0; j < 24; ++j) {
    int o = j * 256 + tid;
    int b = o / 94, w = o - b * 94;
    pre[j] = (o < 6016) ? rowbuf[(size_t)b * 96 + w] : 0ull;
  }
  __syncthreads();

  for (int c = 0; c < 94; ++c) {
#pragma unroll
    for (int j = 0; j < 24; ++j) {
      int o = j * 256 + tid;
      int b = o / 94, w = o - b * 94;
      if (o < 6016) stage[b * 97 + w] = pre[j];
    }
    __syncthreads();
    if (c + 1 < 94) {
#pragma unroll
      for (int j = 0; j < 24; ++j) {
        int o = j * 256 + tid;
        int b = o / 94, w = o - b * 94;
        pre[j] = (o < 6016) ? rowbuf[((size_t)(c + 1) * 64 + b) * 96 + w] : 0ull;
      }
    }
    u64 valid = (c == 93) ? ((1ull << 48) - 1ull) : ~0ull;
    u64 sup_c = sup[c];
    u64 live0 = ~sup_c & valid;
    u64 rw = stage[(tid & 63) * 97 + c];
    u64 live = live0, keep = 0ull;
    while (live) {
      int b = __builtin_ctzll(live);
      keep |= 1ull << b;
      u64 rb = (u64)__shfl((long long)rw, b);
      live &= ~rb;
      live &= ~(1ull << b);
    }
    int baseU = baseU_sh;
    if (tid < 64 && ((keep >> tid) & 1ull)) {
      u64 below = (tid == 0) ? 0ull : (keep & ((1ull << tid) - 1ull));
      int pos = baseU + __popcll(below);
      if (pos < NKEEP) rois[pos] = cand[c * 64 + tid];
    }
    __syncthreads();
    if (tid == 0) baseU_sh = baseU + __popcll(keep);
    if (tid == 64) sup[c] = sup_c | (live0 & ~keep);
    for (int w = c + 1 + tid; w < 94; w += 256) {
      u64 a = sup[w];
      u64 kk = keep;
      while (kk) {
        int b = __builtin_ctzll(kk);
        kk &= kk - 1;
        a |= stage[b * 97 + w];
      }
      sup[w] = a;
    }
    __syncthreads();
    if (baseU_sh >= NKEEP) break;
  }

  int totU = baseU_sh;
  if (totU < NKEEP) {
    if (tid == 0) {
      int s = 0;
      for (int w = 0; w < 94; ++w) { prefS[w] = s; s += __popcll(sup[w]); }
    }
    __syncthreads();
    for (int i = tid; i < TOPN; i += 256) {
      int w = i >> 6, b = i & 63;
      u64 sw = sup[w];
      if ((sw >> b) & 1ull) {
        u64 below = (b == 0) ? 0ull : (sw & ((1ull << b) - 1ull));
        int pos = totU + prefS[w] + __popcll(below);
        if (pos < NKEEP) rois[pos] = cand[i];
      }
    }
  }
}

// ---------------- K7: roi_align, coalesced reads (c=thread) + LDS; write grouped layout ----------------
// smem holds pool row m in k-linear order (k = c*49+s). Final copy emits 16B chunks
// into k8's grouped layout: chunk q (k=q*8..q*8+7) -> (q>>3)*20480 + ((q&7)*320 + m)*8.
__global__ __launch_bounds__(512) void k7_roi(const float4* __restrict__ rois,
    const float* __restrict__ feat_t, unsigned short* __restrict__ pool_bf)
{
  __shared__ __align__(16) unsigned short smem[512 * 49];   // 50176 B
  int m = blockIdx.x;        // 0..319
  int c = threadIdx.x;       // channel
  bool rok = m < NKEEP;
  float4 box = rok ? rois[m] : make_float4(0.f, 0.f, 0.f, 0.f);
  float x1 = box.x * 0.0625f, y1 = box.y * 0.0625f;
  float x2 = box.z * 0.0625f, y2 = box.w * 0.0625f;

#pragma unroll 1
  for (int s = 0; s < 49; ++s) {
    int py = s / 7, px = s - (s / 7) * 7;
    float acc = 0.f;
#pragma unroll
    for (int sy = 0; sy < 2; ++sy) {
#pragma unroll
      for (int sx = 0; sx < 2; ++sx) {
        float offx = ((float)(2 * px + sx) + 0.5f) * 0.5f;
        float offy = ((float)(2 * py + sy) + 0.5f) * 0.5f;
        float xs = x1 + (offx * (x2 - x1)) / 7.f;
        float ys = y1 + (offy * (y2 - y1)) / 7.f;
        float x0f = floorf(xs), y0f = floorf(ys);
        float lx = xs - x0f, ly = ys - y0f;
        int x0i = (int)fminf(fmaxf(x0f, 0.f), 49.f);
        int x1i = (int)fminf(fmaxf(x0f + 1.f, 0.f), 49.f);
        int y0i = (int)fminf(fmaxf(y0f, 0.f), 49.f);
        int y1i = (int)fminf(fmaxf(y0f + 1.f, 0.f), 49.f);
        float f00 = feat_t[(size_t)(y0i * 50 + x0i) * 512 + c];
        float f01 = feat_t[(size_t)(y0i * 50 + x1i) * 512 + c];
        float f10 = feat_t[(size_t)(y1i * 50 + x0i) * 512 + c];
        float f11 = feat_t[(size_t)(y1i * 50 + x1i) * 512 + c];
        float w00 = (1.f - ly) * (1.f - lx), w01 = (1.f - ly) * lx;
        float w10 = ly * (1.f - lx),          w11 = ly * lx;
        acc += w00 * f00 + w01 * f01 + w10 * f10 + w11 * f11;
      }
    }
    smem[c * 49 + s] = rok ? f2bf(acc * 0.25f) : (unsigned short)0;
  }
  __syncthreads();
  // emit 3136 x 16B chunks into the grouped [step][g][m][8] layout
  for (int q = threadIdx.x; q < 3136; q += 512) {
    ushort8 v = *(const ushort8*)(smem + q * 8);
    *(ushort8*)&pool_bf[(size_t)(q >> 3) * 20480 + (((q & 7) * 320 + m) << 3)] = v;
  }
}

// ---------------- K8: fc7 GEMM bf16 MFMA, streaming W (grouped A layout, linear loads) ----------------
__global__ __launch_bounds__(512) void k8_gemm(const unsigned short* __restrict__ Ap,
    const float* __restrict__ W, float* __restrict__ partial, int spk)
{
  __shared__ __align__(16) unsigned short As[8 * 320 * 8];
  __shared__ __align__(16) unsigned short Bs[8 * 128 * 8];
  int tid = threadIdx.x;
  int lane = tid & 63, wv = tid >> 6;
  int wm = wv & 1, wn = wv >> 1;
  int n0 = blockIdx.x * 128;
  int by = blockIdx.y;
  int steps = min(spk, KSTEPS - by * spk);

  f32x4 acc[10][2];
#pragma unroll
  for (int i = 0; i < 10; ++i)
#pragma unroll
    for (int j = 0; j < 2; ++j) acc[i][j] = (f32x4){0.f, 0.f, 0.f, 0.f};

  ushort8 aReg[5];
  float4 wReg[4];

  auto LOAD = [&](int t) {
    size_t abase = (size_t)(by * spk + t) * 20480;
    int k0 = (by * spk + t) * 64;
#pragma unroll
    for (int j = 0; j < 5; ++j)
      aReg[j] = *(const ushort8*)(Ap + abase + (size_t)(j * 512 + tid) * 8);
#pragma unroll
    for (int j = 0; j < 4; ++j) {
      int fq = j * 512 + tid;
      int n = fq >> 4, kq = fq & 15;
      wReg[j] = *(const float4*)(W + (size_t)(n0 + n) * 25088 + k0 + kq * 4);
    }
  };

  LOAD(0);
  for (int t = 0; t < steps; ++t) {
    u64 pk[4];
#pragma unroll
    for (int j = 0; j < 4; ++j) {
      float4 v = wReg[j];
      pk[j] = (u64)f2bf(v.x) | ((u64)f2bf(v.y) << 16)
            | ((u64)f2bf(v.z) << 32) | ((u64)f2bf(v.w) << 48);
    }
    __syncthreads();
#pragma unroll
    for (int j = 0; j < 5; ++j)
      ((ushort8*)As)[j * 512 + tid] = aReg[j];
#pragma unroll
    for (int j = 0; j < 4; ++j) {
      int fq = j * 512 + tid;
      int n = fq >> 4, kq = fq & 15;
      *(u64*)&Bs[((kq >> 1) * 128 + n) * 8 + (kq & 1) * 4] = pk[j];
    }
    __syncthreads();
    if (t + 1 < steps) LOAD(t + 1);
#pragma unroll
    for (int kk = 0; kk < 2; ++kk) {
      int g = kk * 4 + (lane >> 4);
      short8 b0 = ((const short8*)Bs)[g * 128 + wn * 32 + (lane & 15)];
      short8 b1 = ((const short8*)Bs)[g * 128 + wn * 32 + 16 + (lane & 15)];
#pragma unroll
      for (int fm = 0; fm < 10; ++fm) {
        short8 a = ((const short8*)As)[g * 320 + wm * 160 + fm * 16 + (lane & 15)];
        acc[fm][0] = __builtin_amdgcn_mfma_f32_16x16x32_bf16(a, b0, acc[fm][0], 0, 0, 0);
        acc[fm][1] = __builtin_amdgcn_mfma_f32_16x16x32_bf16(a, b1, acc[fm][1], 0, 0, 0);
      }
    }
  }
  float* P = partial + (size_t)(by * 32 + blockIdx.x) * (320 * 128);
#pragma unroll
  for (int fm = 0; fm < 10; ++fm)
#pragma unroll
    for (int fn = 0; fn < 2; ++fn)
#pragma unroll
      for (int r = 0; r < 4; ++r) {
        int m = wm * 160 + fm * 16 + (lane >> 4) * 4 + r;
        int n = wn * 32 + fn * 16 + (lane & 15);
        P[m * 128 + n] = acc[fm][fn][r];
      }
}

// ---------------- K9a: reduce k8 partials -> fc7 f32 (+bias/ReLU) ----------------
__global__ __launch_bounds__(256) void k9a_reduce(const float* __restrict__ partial,
    const float* __restrict__ bias, float* __restrict__ fc7, int KS)
{
  int idx = blockIdx.x * 256 + threadIdx.x;
  if (idx >= 300 * 4096) return;
  int m = idx >> 12, n = idx & 4095;
  int nt = n >> 7, nn = n & 127;
  float s = 0.f;
  for (int ks = 0; ks < KS; ++ks)
    s += partial[((size_t)(ks * 32 + nt) * 320 + m) * 128 + nn];
  s += bias[n];
  fc7[idx] = fmaxf(s, 0.f);
}

// ---------------- K9b: cls/reg heads, one wave per (m, o) dot product ----------------
__global__ __launch_bounds__(256) void k9b_heads(const float* __restrict__ fc7,
    const float* __restrict__ wc, const float* __restrict__ bc,
    const float* __restrict__ wr, const float* __restrict__ br,
    float* __restrict__ out)
{
  int wid = blockIdx.x * 4 + (threadIdx.x >> 6);
  int lane = threadIdx.x & 63;
  if (wid >= 300 * 105) return;
  int m = wid / 105, o = wid - m * 105;
  const float* w; float b;
  if (o < 21) { w = wc + (size_t)o * 4096; b = bc[o]; }
  else        { w = wr + (size_t)(o - 21) * 4096; b = br[o - 21]; }
  const float4* f4 = (const float4*)(fc7 + (size_t)m * 4096);
  const float4* w4 = (const float4*)w;
  float s = 0.f;
#pragma unroll
  for (int i = 0; i < 16; ++i) {
    float4 a = f4[i * 64 + lane];
    float4 ww = w4[i * 64 + lane];
    s += a.x * ww.x + a.y * ww.y + a.z * ww.z + a.w * ww.w;
  }
#pragma unroll
  for (int d = 32; d > 0; d >>= 1) s += __shfl_down(s, d);
  if (lane == 0) {
    s += b;
    if (o < 21) out[m * 21 + o] = s;
    else        out[6300 + m * 84 + (o - 21)] = s;
  }
}

extern "C" void kernel_launch(void* const* d_in, const int* in_sizes, int n_in,
                              void* d_out, int out_size, void* d_ws, size_t ws_size,
                              hipStream_t stream)
{
  (void)in_sizes; (void)n_in; (void)out_size;
  const float* img    = (const float*)d_in[0];
  const float* w_feat = (const float*)d_in[1];
  const float* b_feat = (const float*)d_in[2];
  const float* w_rpn  = (const float*)d_in[3];
  const float* b_rpn  = (const float*)d_in[4];
  const float* w_score= (const float*)d_in[5];
  const float* b_score= (const float*)d_in[6];
  const float* w_delta= (const float*)d_in[7];
  const float* b_delta= (const float*)d_in[8];
  const float* w_fc7  = (const float*)d_in[9];
  const float* b_fc7  = (const float*)d_in[10];
  const float* w_cls  = (const float*)d_in[11];
  const float* b_cls  = (const float*)d_in[12];
  const float* w_reg  = (const float*)d_in[13];
  const float* b_reg  = (const float*)d_in[14];
  float* out = (float*)d_out;

  char* ws = (char*)d_ws;
  size_t off = 0;
  auto alloc = [&](size_t bytes) -> void* {
    void* p = ws + off;
    off = (off + bytes + 511) & ~(size_t)511;
    return p;
  };
  float* feat_t  = (float*)alloc(5120000);
  unsigned short* Fhi = (unsigned short*)alloc((size_t)NPOS * 512 * 2);
  unsigned short* Flo = (unsigned short*)alloc((size_t)NPOS * 512 * 2);
  unsigned short* Whi = (unsigned short*)alloc((size_t)512 * 4608 * 2);
  unsigned short* Wlo = (unsigned short*)alloc((size_t)512 * 4608 * 2);
  float4* boxes  = (float4*)alloc((size_t)NA * 16);
  u64* keys      = (u64*)alloc((size_t)NA * 8);
  int* histbuf   = (int*)alloc((size_t)(NBUCK + 1 + 256) * 4);
  int* hist = histbuf; int* nbig = histbuf + NBUCK; int* wl = histbuf + NBUCK + 1;
  int* bcur      = (int*)alloc((size_t)NBUCK * 4);
  u64* membuf    = (u64*)alloc((size_t)NA * 8);
  u64* membuf2   = (u64*)alloc((size_t)NA * 8);
  float4* cand   = (float4*)alloc((size_t)TOPN * 16);
  float* areas   = (float*)alloc((size_t)TOPN * 4);
  u64* rowbuf    = (u64*)alloc((size_t)TOPN * 96 * 8);
  float4* rois   = (float4*)alloc(NKEEP * 16);
  unsigned short* pool_bf = (unsigned short*)alloc((size_t)KSTEPS * 20480 * 2);
  float* fc7     = (float*)alloc((size_t)300 * 4096 * 4);

  size_t avail = (ws_size > off) ? (ws_size - off) : 0;
  float* P_sh = (float*)(ws + off);
  int KS1 = 8, KS8 = 8;
  while (KS1 > 1 && (size_t)KS1 * 80 * 16384 * 4 > avail) KS1 >>= 1;
  while (KS8 > 1 && (size_t)KS8 * 32 * 320 * 128 * 4 > avail) KS8 >>= 1;
  int klen1 = 768 / KS1;
  int spk8 = (KSTEPS + KS8 - 1) / KS8;

  kw_prep<<<512, 256, 0, stream>>>(w_rpn, Whi, Wlo, histbuf);
  k1_gemm<<<dim3(20, 4, KS1), 256, 0, stream>>>(img, w_feat, P_sh, klen1);
  kred1<<<(NPOS * 512 + 255) / 256, 256, 0, stream>>>(P_sh, b_feat, feat_t, Fhi, Flo, KS1);
  k2_mfma<<<dim3(4, 16, 8), 256, 0, stream>>>(Fhi, Flo, Whi, Wlo, P_sh);
  k3_fused<<<625, 256, 0, stream>>>(P_sh, b_rpn, w_score, b_score, w_delta, b_delta,
                                    boxes, keys, hist);
  k4_scan   <<<1, 1024, 0, stream>>>(hist, bcur, nbig, wl);
  k4_scatter<<<88, 256, 0, stream>>>(keys, bcur, membuf);
  k4_select <<<RANKBLKS + 64, 1024, 0, stream>>>(keys, hist, bcur, nbig, wl,
                                                 membuf, membuf2, boxes, cand, areas);
  k5_iou    <<<dim3(94, 24), 256, 0, stream>>>(cand, areas, rowbuf);
  k6_scan   <<<1, 256, 0, stream>>>(rowbuf, cand, rois);
  k7_roi    <<<320, 512, 0, stream>>>(rois, feat_t, pool_bf);
  k8_gemm   <<<dim3(32, KS8), 512, 0, stream>>>(pool_bf, w_fc7, P_sh, spk8);
  k9a_reduce<<<(300 * 4096 + 255) / 256, 256, 0, stream>>>(P_sh, b_fc7, fc7, KS8);
  k9b_heads<<<(300 * 105 + 3) / 4, 256, 0, stream>>>(fc7, w_cls, b_cls, w_reg, b_reg, out);
}